// Round 15
// baseline (7078.744 us; speedup 1.0000x reference)
//
#include <hip/hip_runtime.h>

// Problem constants
#define B_  128
#define T_  512
#define I_  512
#define H_  1024
#define G4  4096   // 4*H
#define SLOT 262144L   // 256 KB per h slot (B*H*2)

typedef __attribute__((ext_vector_type(8))) short   short8;
typedef __attribute__((ext_vector_type(4))) short   short4v;
typedef __attribute__((ext_vector_type(4))) float   f32x4;
typedef unsigned long long u64;

__device__ __forceinline__ float bf2f(short u){
  return __uint_as_float(((unsigned)(unsigned short)u) << 16);
}
__device__ __forceinline__ short f2bf(float f){
  unsigned u = __float_as_uint(f);
  unsigned r = (u + 0x7FFFu + ((u >> 16) & 1u)) >> 16;  // RNE
  return (short)r;
}
__device__ __forceinline__ float sigm(float x){ return 1.0f/(1.0f + __expf(-x)); }
__device__ __forceinline__ float tanh_(float x){ return 1.0f - 2.0f/(__expf(2.0f*x) + 1.0f); }

// ---------------- fp32 -> bf16 elementwise convert (vectorized x4) ----------------
__global__ __launch_bounds__(256) void cvt_bf16(const float* __restrict__ in,
                                                short* __restrict__ out, int nq){
  int i = blockIdx.x*256 + threadIdx.x;
  if (i >= nq) return;
  float4 v = ((const float4*)in)[i];
  short4v o; o.x = f2bf(v.x); o.y = f2bf(v.y); o.z = f2bf(v.z); o.w = f2bf(v.w);
  ((short4v*)out)[i] = o;
}

// ---------------- W_hh fp32 [4096][1024] -> bf16 MFMA-fragment-swizzled ----------------
// chunk idx c = (((jb*8 + wv)*2 + ct)*16 + ks)*64 + l ; wv = g*2 + kh.
// Represents W[g*1024 + jb*32 + ct*16 + (l&15)][kh*512 + ks*32 + (l>>4)*8 + e]
__global__ __launch_bounds__(256) void swz_whh(const float* __restrict__ W,
                                               short* __restrict__ out){
  int c = blockIdx.x*256 + threadIdx.x;      // 0 .. 524287
  int l = c & 63, ks = (c >> 6) & 15, ct = (c >> 10) & 1, wvv = (c >> 11) & 7, jb = c >> 14;
  int g = wvv >> 1, kh = wvv & 1;
  long row = (long)(g*1024 + jb*32 + ct*16 + (l & 15));
  int col = kh*512 + ks*32 + (l >> 4)*8;
  const float* src = W + row*H_ + col;
  short8 o;
#pragma unroll
  for (int e = 0; e < 8; ++e) o[e] = f2bf(src[e]);
  ((short8*)out)[c] = o;
}

// ---------------- projection GEMM: C[m,n] = sum_k A[m,k]*W[n,k] + bih[n]+bhh[n] ----------------
// C written NATURAL row-major [m][4096] via LDS-staged coalesced 16B stores.
template<int K>
__global__ __launch_bounds__(256) void proj_gemm(const short* __restrict__ A,
                                                 const short* __restrict__ W,
                                                 const float* __restrict__ bih,
                                                 const float* __restrict__ bhh,
                                                 short* __restrict__ C){
  __shared__ __align__(16) short lds[2][2][128*40];  // tiles; reused as C-stage
  const int tid = threadIdx.x;
  const int l  = tid & 63, wv = tid >> 6;
  const int wm = wv >> 1,  wn = wv & 1;
  const int nt = blockIdx.x, mt = blockIdx.y;
  const int r0 = tid >> 2, cb = (tid & 3) * 8;
  const short* Ab = A + (long)(mt*128 + r0)*K + cb;
  const short* Wb = W + (long)(nt*128 + r0)*K + cb;
  const int lo  = r0*40 + cb;
  const int lo2 = lo + 64*40;
  const int NK = K/32;

  short8 pa0 = *(const short8*)(Ab);
  short8 pa1 = *(const short8*)(Ab + 64*K);
  short8 pb0 = *(const short8*)(Wb);
  short8 pb1 = *(const short8*)(Wb + 64*K);
  *(short8*)&lds[0][0][lo]  = pa0;
  *(short8*)&lds[0][0][lo2] = pa1;
  *(short8*)&lds[0][1][lo]  = pb0;
  *(short8*)&lds[0][1][lo2] = pb1;

  f32x4 acc[4][4];
  f32x4 z = {0.f,0.f,0.f,0.f};
#pragma unroll
  for (int i = 0; i < 4; ++i)
#pragma unroll
    for (int j = 0; j < 4; ++j) acc[i][j] = z;

  for (int kt = 0; kt < NK; ++kt){
    __syncthreads();
    if (kt + 1 < NK){
      pa0 = *(const short8*)(Ab + (kt+1)*32);
      pa1 = *(const short8*)(Ab + (kt+1)*32 + 64*K);
      pb0 = *(const short8*)(Wb + (kt+1)*32);
      pb1 = *(const short8*)(Wb + (kt+1)*32 + 64*K);
    }
    const short* As = lds[kt & 1][0];
    const short* Bs = lds[kt & 1][1];
    short8 bfr[4];
#pragma unroll
    for (int nf = 0; nf < 4; ++nf)
      bfr[nf] = *(const short8*)&Bs[(wn*64 + nf*16 + (l & 15))*40 + (l >> 4)*8];
#pragma unroll
    for (int mf = 0; mf < 4; ++mf){
      short8 af = *(const short8*)&As[(wm*64 + mf*16 + (l & 15))*40 + (l >> 4)*8];
#pragma unroll
      for (int nf = 0; nf < 4; ++nf)
        acc[mf][nf] = __builtin_amdgcn_mfma_f32_16x16x32_bf16(af, bfr[nf], acc[mf][nf], 0, 0, 0);
    }
    if (kt + 1 < NK){
      int nb = (kt + 1) & 1;
      *(short8*)&lds[nb][0][lo]  = pa0;
      *(short8*)&lds[nb][0][lo2] = pa1;
      *(short8*)&lds[nb][1][lo]  = pb0;
      *(short8*)&lds[nb][1][lo2] = pb1;
    }
  }

  // ---- staged epilogue: bias + bf16 into LDS [128][132-padded], then 16B stores ----
  __syncthreads();                               // all MFMA-phase ds_reads done
  short* cst = (short*)&lds[0][0][0];            // 128*132 shorts = 33792 B (fits 40960)
#pragma unroll
  for (int nf = 0; nf < 4; ++nf){
    int nc = wn*64 + nf*16 + (l & 15);
    int n  = nt*128 + nc;
    float bs = bih[n] + bhh[n];
#pragma unroll
    for (int mf = 0; mf < 4; ++mf){
#pragma unroll
      for (int r = 0; r < 4; ++r){
        int mr = wm*64 + mf*16 + (l >> 4)*4 + r;   // C/D: row=(l>>4)*4+r, col=l&15
        cst[mr*132 + nc] = f2bf(acc[mf][nf][r] + bs);
      }
    }
  }
  __syncthreads();
  const long m0 = (long)mt*128;
  const int  n0 = nt*128;
#pragma unroll
  for (int i = 0; i < 8; ++i){
    int sid = i*256 + tid;
    int mr = sid >> 4, seg = sid & 15;
    *(short8*)&C[(m0 + mr)*G4 + n0 + seg*8] = *(const short8*)&cst[mr*132 + seg*8];
  }
}

// ---------------- persistent LSTM scan (one launch per layer) ----------------
// grid (bt=8, jb=32) = 256 blocks x 512 thr; 1 block/CU. Group bt = 32 blocks.
// Wave wv = g*2 + kh; W = 32 frags (128 regs), pinned.
// MARKER PROTOCOL (RING): per-step virgin h slot. Producer: 8x 16B sc1 data
// stores -> (out-store + xg-prefetch overlap the ack) -> s_waitcnt vmcnt(5)
// (counted: drains ONLY the data store) -> one 4B marker/wave (sc1). Consumer:
// wave 0 agent-polls the 256 markers -> barrier -> PLAIN cacheable dwordx4
// gather (virgin addresses: L1/L2 cannot be stale; per-dispatch L2 invalidate
// covers cross-layer ring reuse — R7/R8-proven) -> LDS. Same-XCD blocks share
// one L2 fill -> MALL read traffic /4, transactions /8 vs R12's 8B sentinels.
// Deadlock-free: producers never wait on consumers. Fallback (!RING): R11
// flags + agent 2-slot, unchanged. xg NATURAL row-major [m][4096].
//
// h slot layout: chunk (X = jb*64 + l') holds h[bt*16 + (l'&15)]
//   [jb*32 + (l'>>4)*8 + e]. Consumer wave (g,kh): a[ks] = chunk[(kh*16+ks)*64 + l].
// EW thread map: idx = wv*8 + (l>>3); bl = idx&15; jl = (idx>>4)*8 + (l&7).
template<int LAYER, bool RING>
__global__ __launch_bounds__(512, 2) void lstm_scan(
    short* __restrict__ hring,
    const short* __restrict__ Wsw, const short* __restrict__ xg,
    const float* __restrict__ om, const float* __restrict__ hm, const float* __restrict__ cm,
    short* __restrict__ out0, float* __restrict__ dout,
    int* __restrict__ marks,     // RING: [8 bt][512 t][256 jb*8+wv] ints, pre-zeroed
    int* __restrict__ flags)     // fallback: [8 bt][512 t][32 jb], pre-zeroed
{
  const int tid = threadIdx.x;
  const int l = tid & 63, wv = tid >> 6;
  const int bt = blockIdx.x, jb = blockIdx.y;

  // ---- load W fragments once; pin in registers ----
  short8 w0[16], w1[16];
  {
    const short8* wp = (const short8*)Wsw + ((long)((jb*8 + wv)*2)*16)*64 + l;
#pragma unroll
    for (int ks = 0; ks < 16; ++ks) w0[ks] = wp[ks*64];
#pragma unroll
    for (int ks = 0; ks < 16; ++ks) w1[ks] = wp[(16 + ks)*64];
    f32x4* wf0 = (f32x4*)w0;
    f32x4* wf1 = (f32x4*)w1;
#pragma unroll
    for (int i = 0; i < 16; ++i){ asm volatile("" : "+v"(wf0[i])); asm volatile("" : "+v"(wf1[i])); }
  }

  // ---- EW thread map (chunk-aligned): idx = wv*8 + (l>>3) ----
  const int idx = wv*8 + (l >> 3);
  const int bl  = idx & 15;
  const int jl  = ((idx >> 4) << 3) + (l & 7);
  const int jcol = jb*32 + jl;
  const long bj = (long)(bt*16 + bl)*H_ + jcol;
  const float mo = om[bj], mh = hm[bj], mc = cm[bj];
  float c = 0.f;
  const int ct_r = jl >> 4;                          // col-tile of my jl
  const int lane_src = (jl & 15) + ((bl >> 2) << 4); // lane holding (bl, jl)
  const int rr = bl & 3;
  const int kh = wv & 1;

  __shared__ __align__(16) short hbuf[2048*8];    // 32KB staged group h
  __shared__ float red[16*264];                   // [wv*2+ct][lane*4+r], padded
  __shared__ __align__(16) short sstage[512];     // wave-local pack staging
  int* flbase = flags + (long)bt*T_*32;

  // xg natural layout: element base for this thread (+ t*G4 + g*H_)
  const long xbase = (long)(bt*16 + bl)*T_*G4 + jcol;
  short xv0 = xg[xbase], xv1 = xg[xbase + H_], xv2 = xg[xbase + 2*H_], xv3 = xg[xbase + 3*H_];

  for (int t = 0; t < T_; ++t){
    const long slotoff  = RING ? (long)t*SLOT     : (long)(t & 1)*SLOT;
    const long nslotoff = RING ? (long)(t+1)*SLOT : (long)((t+1) & 1)*SLOT;

    if (t > 0){
      if constexpr (RING){
        // ---- wave 0: agent-poll the 256 per-wave markers of step t-1 ----
        if (wv == 0){
          const u64* mk = (const u64*)(marks + ((long)bt*T_ + (t - 1))*256);
          int spins = 0;
          while (true){
            u64 a = __hip_atomic_load(mk + l,      __ATOMIC_RELAXED, __HIP_MEMORY_SCOPE_AGENT);
            u64 b = __hip_atomic_load(mk + 64 + l, __ATOMIC_RELAXED, __HIP_MEMORY_SCOPE_AGENT);
            unsigned m = (unsigned)a & (unsigned)(a >> 32) & (unsigned)b & (unsigned)(b >> 32);
            if (__all(m != 0)) break;                  // markers are exactly 0 or 1
            if (++spins > (1 << 20)) break;            // safety: wrong-answer not hang
            if (spins > 8) __builtin_amdgcn_s_sleep(1);
          }
        }
        __syncthreads();
        __builtin_amdgcn_fence(__ATOMIC_ACQUIRE, "workgroup");  // compiler ordering only
        // ---- PLAIN cacheable gather (virgin addrs; L2 shared within XCD) ----
        const char* hsl = (const char*)hring + slotoff + (long)bt*32768;
        short8 vv[4];
#pragma unroll
        for (int i = 0; i < 4; ++i)
          vv[i] = *(const short8*)(hsl + (long)(wv*256 + i*64 + l)*16);
#pragma unroll
        for (int i = 0; i < 4; ++i)
          *(short8*)&hbuf[(wv*256 + i*64 + l)*8] = vv[i];
      } else {
        // fallback: flag-gated agent gather (R11)
        const u64* hp = (const u64*)((const char*)hring + slotoff + (long)bt*32768);
        short8 vv[4];
#pragma unroll
        for (int i = 0; i < 4; ++i){
          const u64* ap = hp + (long)(wv*256 + i*64 + l)*2;
          union { u64 q[2]; short8 s; } uu;
          uu.q[0] = __hip_atomic_load(ap,     __ATOMIC_RELAXED, __HIP_MEMORY_SCOPE_AGENT);
          uu.q[1] = __hip_atomic_load(ap + 1, __ATOMIC_RELAXED, __HIP_MEMORY_SCOPE_AGENT);
          vv[i] = uu.s;
        }
#pragma unroll
        for (int i = 0; i < 4; ++i)
          *(short8*)&hbuf[(wv*256 + i*64 + l)*8] = vv[i];
      }
      __syncthreads();

      // ---- 32 MFMA: 2 col-tiles x 16 ks (own K-half only), 4 acc chains ----
      f32x4 a00 = {0.f,0.f,0.f,0.f}, a01 = {0.f,0.f,0.f,0.f};
      f32x4 a10 = {0.f,0.f,0.f,0.f}, a11 = {0.f,0.f,0.f,0.f};
#pragma unroll
      for (int ks = 0; ks < 16; ++ks){
        short8 av = *(const short8*)&hbuf[((kh*16 + ks)*64 + l)*8];
        if (ks & 1){
          a01 = __builtin_amdgcn_mfma_f32_16x16x32_bf16(av, w0[ks], a01, 0, 0, 0);
          a11 = __builtin_amdgcn_mfma_f32_16x16x32_bf16(av, w1[ks], a11, 0, 0, 0);
        } else {
          a00 = __builtin_amdgcn_mfma_f32_16x16x32_bf16(av, w0[ks], a00, 0, 0, 0);
          a10 = __builtin_amdgcn_mfma_f32_16x16x32_bf16(av, w1[ks], a10, 0, 0, 0);
        }
      }
      f32x4 s0, s1;
#pragma unroll
      for (int r = 0; r < 4; ++r){ s0[r] = a00[r] + a01[r]; s1[r] = a10[r] + a11[r]; }
      *(f32x4*)&red[(wv*2 + 0)*264 + l*4] = s0;
      *(f32x4*)&red[(wv*2 + 1)*264 + l*4] = s1;
      __syncthreads();
    }

    // ---- elementwise (thread owns (bl, jl)) ----
    float gate[4];
    short xvv[4] = {xv0, xv1, xv2, xv3};
#pragma unroll
    for (int g = 0; g < 4; ++g){
      float rv = 0.f;
      if (t > 0){
        rv = red[((g*2 + 0)*2 + ct_r)*264 + lane_src*4 + rr]
           + red[((g*2 + 1)*2 + ct_r)*264 + lane_src*4 + rr];
      }
      gate[g] = rv + bf2f(xvv[g]);
    }
    float ii = sigm(gate[0]);
    float ff = sigm(gate[1]);
    float gg = tanh_(gate[2]);
    float oo = sigm(gate[3]);
    float c2 = ff*c + ii*gg;
    float h2 = oo*tanh_(c2);
    c = c2*mc;
    float hn = h2*mh;

    if (t == T_ - 1){
      if (LAYER == 0){
        out0[((long)(bt*16 + bl)*T_ + t)*H_ + jcol] = f2bf(h2*mo);
      } else {
        dout[((long)(bt*16 + bl)*T_ + t)*H_ + jcol] = h2*mo;
        dout[(long)B_*T_*H_ + bj] = hn;                    // hf
        dout[(long)B_*T_*H_ + (long)B_*H_ + bj] = c;       // cf
      }
      break;
    }

    // ---- wave-local pack: lane l -> sstage[wv*64+l]; lanes<8 store chunks ----
    sstage[wv*64 + l] = f2bf(hn);
    asm volatile("s_waitcnt lgkmcnt(0)" ::: "memory");   // own wave's ds_write done
    __builtin_amdgcn_sched_barrier(0);
    if (l < 8){
      short8 pk = *(const short8*)&sstage[wv*64 + l*8];
      char* hdst = (char*)hring + nslotoff
                 + ((long)bt*2048 + jb*64 + wv*8 + l)*16;
      if constexpr (RING){
        asm volatile("global_store_dwordx4 %0, %1, off sc1" :: "v"(hdst), "v"(pk) : "memory");
      } else {
        union { short8 s; u64 q[2]; } uu; uu.s = pk;
        u64* qp = (u64*)hdst;
        __hip_atomic_store(qp,     uu.q[0], __ATOMIC_RELAXED, __HIP_MEMORY_SCOPE_AGENT);
        __hip_atomic_store(qp + 1, uu.q[1], __ATOMIC_RELAXED, __HIP_MEMORY_SCOPE_AGENT);
      }
    }

    if constexpr (RING){
      // ---- overlap HBM ops under the data-store ack (exactly 5 vm-ops) ----
      if (LAYER == 0){
        out0[((long)(bt*16 + bl)*T_ + t)*H_ + jcol] = f2bf(h2*mo);
      } else {
        dout[((long)(bt*16 + bl)*T_ + t)*H_ + jcol] = h2*mo;
      }
      {
        const short* xp = xg + xbase + (long)(t + 1)*G4;
        xv0 = xp[0]; xv1 = xp[H_]; xv2 = xp[2*H_]; xv3 = xp[3*H_];
      }
      // counted drain: 5 vm-ops issued after the data store -> waits ONLY it
      asm volatile("s_waitcnt vmcnt(5)" ::: "memory");
      if (l == 0){
        int one = 1;
        int* mp = marks + ((long)bt*T_ + t)*256 + jb*8 + wv;
        asm volatile("global_store_dword %0, %1, off sc1" :: "v"(mp), "v"(one) : "memory");
      }
    } else {
      asm volatile("s_waitcnt vmcnt(0)" ::: "memory");   // h at coherence point
      __syncthreads();
      if (tid == 0)
        __hip_atomic_store(&flbase[(long)t*32 + jb], 1,
                           __ATOMIC_RELAXED, __HIP_MEMORY_SCOPE_AGENT);
      if (LAYER == 0){
        out0[((long)(bt*16 + bl)*T_ + t)*H_ + jcol] = f2bf(h2*mo);
      } else {
        dout[((long)(bt*16 + bl)*T_ + t)*H_ + jcol] = h2*mo;
      }
      {
        const short* xp = xg + xbase + (long)(t + 1)*G4;
        xv0 = xp[0]; xv1 = xp[H_]; xv2 = xp[2*H_]; xv3 = xp[3*H_];
      }
      // poll 32 packed flags (16 lanes x u64)
      const u64* fp = (const u64*)&flbase[(long)t*32];
      int spins = 0;
      while (true){
        int ok = 1;
        if (l < 16){
          u64 v = __hip_atomic_load(fp + l, __ATOMIC_RELAXED, __HIP_MEMORY_SCOPE_AGENT);
          ok = ((unsigned)v != 0u) & ((unsigned)(v >> 32) != 0u);
        }
        if (__all(ok)) break;
        if (++spins > (1 << 20)) break;
        if (spins > 8) __builtin_amdgcn_s_sleep(1);
      }
      __builtin_amdgcn_sched_barrier(0);
      __builtin_amdgcn_fence(__ATOMIC_ACQUIRE, "workgroup");
    }
  }
}

extern "C" void kernel_launch(void* const* d_in, const int* in_sizes, int n_in,
                              void* d_out, int out_size, void* d_ws, size_t ws_size,
                              hipStream_t stream){
  const float* x    = (const float*)d_in[0];
  const float* Wih0 = (const float*)d_in[1];
  const float* Whh0 = (const float*)d_in[2];
  const float* bih0 = (const float*)d_in[3];
  const float* bhh0 = (const float*)d_in[4];
  const float* Wih1 = (const float*)d_in[5];
  const float* Whh1 = (const float*)d_in[6];
  const float* bih1 = (const float*)d_in[7];
  const float* bhh1 = (const float*)d_in[8];
  const float* omsk = (const float*)d_in[9];
  const float* hmsk = (const float*)d_in[10];
  const float* cmsk = (const float*)d_in[11];
  float* out = (float*)d_out;

  char* p = (char*)d_ws;
  auto alloc = [&](size_t bytes)->char*{
    char* r = p; p += (bytes + 255) & ~(size_t)255; return r;
  };
  short* xg      = (short*)alloc((size_t)65536*4096*2);   // 512 MB xg, natural [m][4096]
  short* out0_bf = (short*)alloc((size_t)67108864*2);     // 128 MB layer-0 outputs
  short* x_bf    = (short*)out0_bf;                       // 64 MB alias (dead before out0 written)
  short* wih0_bf = (short*)alloc((size_t)2097152*2);
  short* wih1_bf = (short*)alloc((size_t)4194304*2);
  short* whh0_sw = (short*)alloc((size_t)4194304*2);
  short* whh1_sw = (short*)alloc((size_t)4194304*2);
  int*   marks0  = (int*)alloc((size_t)8*512*256*4);      // 4 MB markers (RING)
  int*   marks1  = (int*)alloc((size_t)8*512*256*4);
  int*   flags0  = (int*)alloc((size_t)8*512*32*4);       // fallback flags
  int*   flags1  = (int*)alloc((size_t)8*512*32*4);
  // ring if it fits, else 2-slot ping-pong fallback
  size_t fixed = (size_t)(p - (char*)d_ws);
  bool ring = (fixed + (size_t)512*SLOT) <= ws_size;
  size_t ringbytes = ring ? (size_t)512*SLOT : (size_t)2*SLOT;
  short* hring = (short*)alloc(ringbytes);
  if ((size_t)(p - (char*)d_ws) > ws_size) return;   // cannot even fit fallback — bail

  // markers/flags re-zeroed every call (deterministic across graph replays).
  // h ring needs NO init: t=0 skips the h path and reads are marker-gated.
  hipMemsetAsync(marks0, 0, (size_t)8*512*256*4, stream);
  hipMemsetAsync(marks1, 0, (size_t)8*512*256*4, stream);
  hipMemsetAsync(flags0, 0, (size_t)8*512*32*4, stream);
  hipMemsetAsync(flags1, 0, (size_t)8*512*32*4, stream);

  // converts / weight swizzles
  cvt_bf16<<<33554432/4/256, 256, 0, stream>>>(x,    x_bf,    33554432/4);
  cvt_bf16<<<2097152/4/256,  256, 0, stream>>>(Wih0, wih0_bf, 2097152/4);
  cvt_bf16<<<4194304/4/256,  256, 0, stream>>>(Wih1, wih1_bf, 4194304/4);
  swz_whh <<<524288/256,     256, 0, stream>>>(Whh0, whh0_sw);
  swz_whh <<<524288/256,     256, 0, stream>>>(Whh1, whh1_sw);

  // ---- layer 0 ----
  proj_gemm<512><<<dim3(32, 512), 256, 0, stream>>>(x_bf, wih0_bf, bih0, bhh0, xg);
  if (ring)
    lstm_scan<0, true ><<<dim3(8, 32), 512, 0, stream>>>(hring, whh0_sw, xg,
        omsk, hmsk, cmsk, out0_bf, nullptr, marks0, flags0);
  else
    lstm_scan<0, false><<<dim3(8, 32), 512, 0, stream>>>(hring, whh0_sw, xg,
        omsk, hmsk, cmsk, out0_bf, nullptr, marks0, flags0);

  // ---- layer 1 ----
  proj_gemm<1024><<<dim3(32, 512), 256, 0, stream>>>(out0_bf, wih1_bf, bih1, bhh1, xg);
  if (ring)
    lstm_scan<1, true ><<<dim3(8, 32), 512, 0, stream>>>(hring, whh1_sw, xg,
        omsk + 131072, hmsk + 131072, cmsk + 131072, nullptr, out, marks1, flags1);
  else
    lstm_scan<1, false><<<dim3(8, 32), 512, 0, stream>>>(hring, whh1_sw, xg,
        omsk + 131072, hmsk + 131072, cmsk + 131072, nullptr, out, marks1, flags1);
}

// Round 16
// 4092.776 us; speedup vs baseline: 1.7296x; 1.7296x over previous
//
#include <hip/hip_runtime.h>

// Problem constants
#define B_  128
#define T_  512
#define I_  512
#define H_  1024
#define G4  4096   // 4*H
#define SLOT 262144L   // 256 KB per h slot (B*H*2)
#define SENTW 0xFFFFFFFFu

typedef __attribute__((ext_vector_type(8))) short   short8;
typedef __attribute__((ext_vector_type(4))) short   short4v;
typedef __attribute__((ext_vector_type(4))) float   f32x4;
typedef unsigned long long u64;

__device__ __forceinline__ float bf2f(short u){
  return __uint_as_float(((unsigned)(unsigned short)u) << 16);
}
__device__ __forceinline__ short f2bf(float f){
  unsigned u = __float_as_uint(f);
  unsigned r = (u + 0x7FFFu + ((u >> 16) & 1u)) >> 16;  // RNE
  return (short)r;
}
__device__ __forceinline__ float sigm(float x){ return 1.0f/(1.0f + __expf(-x)); }
__device__ __forceinline__ float tanh_(float x){ return 1.0f - 2.0f/(__expf(2.0f*x) + 1.0f); }
__device__ __forceinline__ bool okq(u64 a){
  return ((unsigned)a != SENTW) & ((unsigned)(a >> 32) != SENTW);
}

// ---------------- fp32 -> bf16 elementwise convert (vectorized x4) ----------------
__global__ __launch_bounds__(256) void cvt_bf16(const float* __restrict__ in,
                                                short* __restrict__ out, int nq){
  int i = blockIdx.x*256 + threadIdx.x;
  if (i >= nq) return;
  float4 v = ((const float4*)in)[i];
  short4v o; o.x = f2bf(v.x); o.y = f2bf(v.y); o.z = f2bf(v.z); o.w = f2bf(v.w);
  ((short4v*)out)[i] = o;
}

// ---------------- W_hh fp32 [4096][1024] -> bf16 MFMA-fragment-swizzled ----------------
// chunk idx c = (((jb*8 + wv)*2 + ct)*16 + ks)*64 + l ; wv = g*2 + kh.
// Represents W[g*1024 + jb*32 + ct*16 + (l&15)][kh*512 + ks*32 + (l>>4)*8 + e]
__global__ __launch_bounds__(256) void swz_whh(const float* __restrict__ W,
                                               short* __restrict__ out){
  int c = blockIdx.x*256 + threadIdx.x;      // 0 .. 524287
  int l = c & 63, ks = (c >> 6) & 15, ct = (c >> 10) & 1, wvv = (c >> 11) & 7, jb = c >> 14;
  int g = wvv >> 1, kh = wvv & 1;
  long row = (long)(g*1024 + jb*32 + ct*16 + (l & 15));
  int col = kh*512 + ks*32 + (l >> 4)*8;
  const float* src = W + row*H_ + col;
  short8 o;
#pragma unroll
  for (int e = 0; e < 8; ++e) o[e] = f2bf(src[e]);
  ((short8*)out)[c] = o;
}

// ---------------- projection GEMM: C[m,n] = sum_k A[m,k]*W[n,k] + bih[n]+bhh[n] ----------------
// C written NATURAL row-major [m][4096] via LDS-staged coalesced 16B stores.
template<int K>
__global__ __launch_bounds__(256) void proj_gemm(const short* __restrict__ A,
                                                 const short* __restrict__ W,
                                                 const float* __restrict__ bih,
                                                 const float* __restrict__ bhh,
                                                 short* __restrict__ C){
  __shared__ __align__(16) short lds[2][2][128*40];  // tiles; reused as C-stage
  const int tid = threadIdx.x;
  const int l  = tid & 63, wv = tid >> 6;
  const int wm = wv >> 1,  wn = wv & 1;
  const int nt = blockIdx.x, mt = blockIdx.y;
  const int r0 = tid >> 2, cb = (tid & 3) * 8;
  const short* Ab = A + (long)(mt*128 + r0)*K + cb;
  const short* Wb = W + (long)(nt*128 + r0)*K + cb;
  const int lo  = r0*40 + cb;
  const int lo2 = lo + 64*40;
  const int NK = K/32;

  short8 pa0 = *(const short8*)(Ab);
  short8 pa1 = *(const short8*)(Ab + 64*K);
  short8 pb0 = *(const short8*)(Wb);
  short8 pb1 = *(const short8*)(Wb + 64*K);
  *(short8*)&lds[0][0][lo]  = pa0;
  *(short8*)&lds[0][0][lo2] = pa1;
  *(short8*)&lds[0][1][lo]  = pb0;
  *(short8*)&lds[0][1][lo2] = pb1;

  f32x4 acc[4][4];
  f32x4 z = {0.f,0.f,0.f,0.f};
#pragma unroll
  for (int i = 0; i < 4; ++i)
#pragma unroll
    for (int j = 0; j < 4; ++j) acc[i][j] = z;

  for (int kt = 0; kt < NK; ++kt){
    __syncthreads();
    if (kt + 1 < NK){
      pa0 = *(const short8*)(Ab + (kt+1)*32);
      pa1 = *(const short8*)(Ab + (kt+1)*32 + 64*K);
      pb0 = *(const short8*)(Wb + (kt+1)*32);
      pb1 = *(const short8*)(Wb + (kt+1)*32 + 64*K);
    }
    const short* As = lds[kt & 1][0];
    const short* Bs = lds[kt & 1][1];
    short8 bfr[4];
#pragma unroll
    for (int nf = 0; nf < 4; ++nf)
      bfr[nf] = *(const short8*)&Bs[(wn*64 + nf*16 + (l & 15))*40 + (l >> 4)*8];
#pragma unroll
    for (int mf = 0; mf < 4; ++mf){
      short8 af = *(const short8*)&As[(wm*64 + mf*16 + (l & 15))*40 + (l >> 4)*8];
#pragma unroll
      for (int nf = 0; nf < 4; ++nf)
        acc[mf][nf] = __builtin_amdgcn_mfma_f32_16x16x32_bf16(af, bfr[nf], acc[mf][nf], 0, 0, 0);
    }
    if (kt + 1 < NK){
      int nb = (kt + 1) & 1;
      *(short8*)&lds[nb][0][lo]  = pa0;
      *(short8*)&lds[nb][0][lo2] = pa1;
      *(short8*)&lds[nb][1][lo]  = pb0;
      *(short8*)&lds[nb][1][lo2] = pb1;
    }
  }

  // ---- staged epilogue: bias + bf16 into LDS [128][132-padded], then 16B stores ----
  __syncthreads();                               // all MFMA-phase ds_reads done
  short* cst = (short*)&lds[0][0][0];            // 128*132 shorts = 33792 B (fits 40960)
#pragma unroll
  for (int nf = 0; nf < 4; ++nf){
    int nc = wn*64 + nf*16 + (l & 15);
    int n  = nt*128 + nc;
    float bs = bih[n] + bhh[n];
#pragma unroll
    for (int mf = 0; mf < 4; ++mf){
#pragma unroll
      for (int r = 0; r < 4; ++r){
        int mr = wm*64 + mf*16 + (l >> 4)*4 + r;   // C/D: row=(l>>4)*4+r, col=l&15
        cst[mr*132 + nc] = f2bf(acc[mf][nf][r] + bs);
      }
    }
  }
  __syncthreads();
  const long m0 = (long)mt*128;
  const int  n0 = nt*128;
#pragma unroll
  for (int i = 0; i < 8; ++i){
    int sid = i*256 + tid;
    int mr = sid >> 4, seg = sid & 15;
    *(short8*)&C[(m0 + mr)*G4 + n0 + seg*8] = *(const short8*)&cst[mr*132 + seg*8];
  }
}

// ---------------- persistent LSTM scan (one launch per layer) ----------------
// grid (bt=8, jb=32) = 256 blocks x 512 thr; 1 block/CU. Group bt = 32 blocks.
// Wave wv = g*2 + kh; W = 32 frags (128 regs), pinned. SENTINEL PROTOCOL (RING,
// R12/R14-proven): ring pre-filled 0xFF (bf16 NaN, unreachable by f2bf of finite
// h). Producer: pack (wave-local LDS) -> 8x dwordx4 sc1 fire-and-forget.
// Consumer: agent-scope u64 atomic poll-gather of its 4 chunks until no dword
// == sentinel (the gather IS the sync; ONE MALL RT — R15 proved any 2-RT split
// doubles step time). NOTE: must use __hip_atomic_load AGENT — hand-rolled
// `sc1`-only loads do NOT refresh a stale cached line (R13 NaN).
// Slots write-once per call per layer. Deadlock-free: producers never wait.
// Fallback (!RING): flags + agent 2-slot (R11). xg NATURAL row-major [m][4096].
//
// h slot layout: chunk (X = jb*64 + l') holds h[bt*16 + (l'&15)]
//   [jb*32 + (l'>>4)*8 + e]. Consumer wave (g,kh): a[ks] = chunk[(kh*16+ks)*64 + l].
// EW thread map: idx = wv*8 + (l>>3); bl = idx&15; jl = (idx>>4)*8 + (l&7).
template<int LAYER, bool RING>
__global__ __launch_bounds__(512, 2) void lstm_scan(
    short* __restrict__ hring,
    const short* __restrict__ Wsw, const short* __restrict__ xg,
    const float* __restrict__ om, const float* __restrict__ hm, const float* __restrict__ cm,
    short* __restrict__ out0, float* __restrict__ dout,
    int* __restrict__ flags)     // fallback only: [8 bt][512 t][32 jb], pre-zeroed
{
  const int tid = threadIdx.x;
  const int l = tid & 63, wv = tid >> 6;
  const int bt = blockIdx.x, jb = blockIdx.y;

  // ---- load W fragments once; pin in registers ----
  short8 w0[16], w1[16];
  {
    const short8* wp = (const short8*)Wsw + ((long)((jb*8 + wv)*2)*16)*64 + l;
#pragma unroll
    for (int ks = 0; ks < 16; ++ks) w0[ks] = wp[ks*64];
#pragma unroll
    for (int ks = 0; ks < 16; ++ks) w1[ks] = wp[(16 + ks)*64];
    f32x4* wf0 = (f32x4*)w0;
    f32x4* wf1 = (f32x4*)w1;
#pragma unroll
    for (int i = 0; i < 16; ++i){ asm volatile("" : "+v"(wf0[i])); asm volatile("" : "+v"(wf1[i])); }
  }

  // ---- EW thread map (chunk-aligned): idx = wv*8 + (l>>3) ----
  const int idx = wv*8 + (l >> 3);
  const int bl  = idx & 15;
  const int jl  = ((idx >> 4) << 3) + (l & 7);
  const int jcol = jb*32 + jl;
  const long bj = (long)(bt*16 + bl)*H_ + jcol;
  const float mo = om[bj], mh = hm[bj], mc = cm[bj];
  float c = 0.f;
  const int ct_r = jl >> 4;                          // col-tile of my jl
  const int lane_src = (jl & 15) + ((bl >> 2) << 4); // lane holding (bl, jl)
  const int rr = bl & 3;
  const int kh = wv & 1;

  __shared__ __align__(16) short hbuf[2048*8];    // 32KB staged group h
  __shared__ float red[16*264];                   // [wv*2+ct][lane*4+r], padded
  __shared__ __align__(16) short sstage[512];     // wave-local pack staging
  int* flbase = flags + (long)bt*T_*32;

  // per-thread gather offsets (u64 units within slot's bt region)
  const long go0 = (long)(wv*256 + 0*64 + l)*2;
  const long go1 = (long)(wv*256 + 1*64 + l)*2;
  const long go2 = (long)(wv*256 + 2*64 + l)*2;
  const long go3 = (long)(wv*256 + 3*64 + l)*2;

  // xg natural layout: element base for this thread (+ t*G4 + g*H_)
  const long xbase = (long)(bt*16 + bl)*T_*G4 + jcol;
  short xv0 = xg[xbase], xv1 = xg[xbase + H_], xv2 = xg[xbase + 2*H_], xv3 = xg[xbase + 3*H_];

  for (int t = 0; t < T_; ++t){
    const long slotoff  = RING ? (long)t*SLOT     : (long)(t & 1)*SLOT;
    const long nslotoff = RING ? (long)(t+1)*SLOT : (long)((t+1) & 1)*SLOT;

    if (t > 0){
      const u64* hp = (const u64*)((const char*)hring + slotoff + (long)bt*32768);
      if constexpr (RING){
        // ---- sentinel poll-gather (R12-proven): arrival test IS the data read ----
        u64 q0=0,q1=0,q2=0,q3=0,q4=0,q5=0,q6=0,q7=0;
        int ok = 0, spins = 0;
        while (true){
          if (!(ok & 1)){
            u64 a = __hip_atomic_load(hp + go0,     __ATOMIC_RELAXED, __HIP_MEMORY_SCOPE_AGENT);
            u64 b = __hip_atomic_load(hp + go0 + 1, __ATOMIC_RELAXED, __HIP_MEMORY_SCOPE_AGENT);
            if (okq(a) & okq(b)){ q0 = a; q1 = b; ok |= 1; }
          }
          if (!(ok & 2)){
            u64 a = __hip_atomic_load(hp + go1,     __ATOMIC_RELAXED, __HIP_MEMORY_SCOPE_AGENT);
            u64 b = __hip_atomic_load(hp + go1 + 1, __ATOMIC_RELAXED, __HIP_MEMORY_SCOPE_AGENT);
            if (okq(a) & okq(b)){ q2 = a; q3 = b; ok |= 2; }
          }
          if (!(ok & 4)){
            u64 a = __hip_atomic_load(hp + go2,     __ATOMIC_RELAXED, __HIP_MEMORY_SCOPE_AGENT);
            u64 b = __hip_atomic_load(hp + go2 + 1, __ATOMIC_RELAXED, __HIP_MEMORY_SCOPE_AGENT);
            if (okq(a) & okq(b)){ q4 = a; q5 = b; ok |= 4; }
          }
          if (!(ok & 8)){
            u64 a = __hip_atomic_load(hp + go3,     __ATOMIC_RELAXED, __HIP_MEMORY_SCOPE_AGENT);
            u64 b = __hip_atomic_load(hp + go3 + 1, __ATOMIC_RELAXED, __HIP_MEMORY_SCOPE_AGENT);
            if (okq(a) & okq(b)){ q6 = a; q7 = b; ok |= 8; }
          }
          if (ok == 15) break;
          if (++spins > (1 << 20)) break;   // safety: wrong-answer instead of hang
          if (spins > 2) __builtin_amdgcn_s_sleep(2);
        }
        union { u64 u[2]; short8 s; } c0, c1, c2_, c3;
        c0.u[0] = q0; c0.u[1] = q1;  c1.u[0] = q2; c1.u[1] = q3;
        c2_.u[0] = q4; c2_.u[1] = q5; c3.u[0] = q6; c3.u[1] = q7;
        *(short8*)&hbuf[(wv*256 +   0 + l)*8] = c0.s;
        *(short8*)&hbuf[(wv*256 +  64 + l)*8] = c1.s;
        *(short8*)&hbuf[(wv*256 + 128 + l)*8] = c2_.s;
        *(short8*)&hbuf[(wv*256 + 192 + l)*8] = c3.s;
      } else {
        // fallback: flag-gated agent gather (R11)
        short8 vv[4];
#pragma unroll
        for (int i = 0; i < 4; ++i){
          const u64* ap = hp + (long)(wv*256 + i*64 + l)*2;
          union { u64 q[2]; short8 s; } uu;
          uu.q[0] = __hip_atomic_load(ap,     __ATOMIC_RELAXED, __HIP_MEMORY_SCOPE_AGENT);
          uu.q[1] = __hip_atomic_load(ap + 1, __ATOMIC_RELAXED, __HIP_MEMORY_SCOPE_AGENT);
          vv[i] = uu.s;
        }
#pragma unroll
        for (int i = 0; i < 4; ++i)
          *(short8*)&hbuf[(wv*256 + i*64 + l)*8] = vv[i];
      }
      __syncthreads();

      // ---- 32 MFMA: 2 col-tiles x 16 ks (own K-half only), 4 acc chains ----
      f32x4 a00 = {0.f,0.f,0.f,0.f}, a01 = {0.f,0.f,0.f,0.f};
      f32x4 a10 = {0.f,0.f,0.f,0.f}, a11 = {0.f,0.f,0.f,0.f};
#pragma unroll
      for (int ks = 0; ks < 16; ++ks){
        short8 av = *(const short8*)&hbuf[((kh*16 + ks)*64 + l)*8];
        if (ks & 1){
          a01 = __builtin_amdgcn_mfma_f32_16x16x32_bf16(av, w0[ks], a01, 0, 0, 0);
          a11 = __builtin_amdgcn_mfma_f32_16x16x32_bf16(av, w1[ks], a11, 0, 0, 0);
        } else {
          a00 = __builtin_amdgcn_mfma_f32_16x16x32_bf16(av, w0[ks], a00, 0, 0, 0);
          a10 = __builtin_amdgcn_mfma_f32_16x16x32_bf16(av, w1[ks], a10, 0, 0, 0);
        }
      }
      f32x4 s0, s1;
#pragma unroll
      for (int r = 0; r < 4; ++r){ s0[r] = a00[r] + a01[r]; s1[r] = a10[r] + a11[r]; }
      *(f32x4*)&red[(wv*2 + 0)*264 + l*4] = s0;
      *(f32x4*)&red[(wv*2 + 1)*264 + l*4] = s1;
      __syncthreads();
    }

    // ---- elementwise (thread owns (bl, jl)) ----
    float gate[4];
    short xvv[4] = {xv0, xv1, xv2, xv3};
#pragma unroll
    for (int g = 0; g < 4; ++g){
      float rv = 0.f;
      if (t > 0){
        rv = red[((g*2 + 0)*2 + ct_r)*264 + lane_src*4 + rr]
           + red[((g*2 + 1)*2 + ct_r)*264 + lane_src*4 + rr];
      }
      gate[g] = rv + bf2f(xvv[g]);
    }
    float ii = sigm(gate[0]);
    float ff = sigm(gate[1]);
    float gg = tanh_(gate[2]);
    float oo = sigm(gate[3]);
    float c2 = ff*c + ii*gg;
    float h2 = oo*tanh_(c2);
    c = c2*mc;
    float hn = h2*mh;

    if (t == T_ - 1){
      if (LAYER == 0){
        out0[((long)(bt*16 + bl)*T_ + t)*H_ + jcol] = f2bf(h2*mo);
      } else {
        dout[((long)(bt*16 + bl)*T_ + t)*H_ + jcol] = h2*mo;
        dout[(long)B_*T_*H_ + bj] = hn;                    // hf
        dout[(long)B_*T_*H_ + (long)B_*H_ + bj] = c;       // cf
      }
      break;
    }

    // ---- wave-local pack: lane l -> sstage[wv*64+l]; lanes<8 store chunks ----
    sstage[wv*64 + l] = f2bf(hn);
    asm volatile("s_waitcnt lgkmcnt(0)" ::: "memory");   // own wave's ds_write done
    __builtin_amdgcn_sched_barrier(0);
    if (l < 8){
      short8 pk = *(const short8*)&sstage[wv*64 + l*8];
      char* hdst = (char*)hring + nslotoff
                 + ((long)bt*2048 + jb*64 + wv*8 + l)*16;
      if constexpr (RING){
        // fire-and-forget: sentinel protocol needs no ack
        asm volatile("global_store_dwordx4 %0, %1, off sc1" :: "v"(hdst), "v"(pk) : "memory");
      } else {
        union { short8 s; u64 q[2]; } uu; uu.s = pk;
        u64* qp = (u64*)hdst;
        __hip_atomic_store(qp,     uu.q[0], __ATOMIC_RELAXED, __HIP_MEMORY_SCOPE_AGENT);
        __hip_atomic_store(qp + 1, uu.q[1], __ATOMIC_RELAXED, __HIP_MEMORY_SCOPE_AGENT);
      }
    }
    if constexpr (!RING){
      asm volatile("s_waitcnt vmcnt(0)" ::: "memory");   // h at coherence point
      __syncthreads();
      if (tid == 0)
        __hip_atomic_store(&flbase[(long)t*32 + jb], 1,
                           __ATOMIC_RELAXED, __HIP_MEMORY_SCOPE_AGENT);
    }

    // ---- out stores + xg prefetch (overlap next-step poll/gather) ----
    if (LAYER == 0){
      out0[((long)(bt*16 + bl)*T_ + t)*H_ + jcol] = f2bf(h2*mo);
    } else {
      dout[((long)(bt*16 + bl)*T_ + t)*H_ + jcol] = h2*mo;
    }
    {
      const short* xp = xg + xbase + (long)(t + 1)*G4;
      xv0 = xp[0]; xv1 = xp[H_]; xv2 = xp[2*H_]; xv3 = xp[3*H_];
    }

    if constexpr (!RING){
      // fallback: poll 32 packed flags (16 lanes x u64)
      const u64* fp = (const u64*)&flbase[(long)t*32];
      int spins = 0;
      while (true){
        int ok = 1;
        if (l < 16){
          u64 v = __hip_atomic_load(fp + l, __ATOMIC_RELAXED, __HIP_MEMORY_SCOPE_AGENT);
          ok = ((unsigned)v != 0u) & ((unsigned)(v >> 32) != 0u);
        }
        if (__all(ok)) break;
        if (++spins > (1 << 20)) break;
        if (spins > 8) __builtin_amdgcn_s_sleep(1);
      }
      __builtin_amdgcn_sched_barrier(0);
      __builtin_amdgcn_fence(__ATOMIC_ACQUIRE, "workgroup");
    }
  }
}

extern "C" void kernel_launch(void* const* d_in, const int* in_sizes, int n_in,
                              void* d_out, int out_size, void* d_ws, size_t ws_size,
                              hipStream_t stream){
  const float* x    = (const float*)d_in[0];
  const float* Wih0 = (const float*)d_in[1];
  const float* Whh0 = (const float*)d_in[2];
  const float* bih0 = (const float*)d_in[3];
  const float* bhh0 = (const float*)d_in[4];
  const float* Wih1 = (const float*)d_in[5];
  const float* Whh1 = (const float*)d_in[6];
  const float* bih1 = (const float*)d_in[7];
  const float* bhh1 = (const float*)d_in[8];
  const float* omsk = (const float*)d_in[9];
  const float* hmsk = (const float*)d_in[10];
  const float* cmsk = (const float*)d_in[11];
  float* out = (float*)d_out;

  char* p = (char*)d_ws;
  auto alloc = [&](size_t bytes)->char*{
    char* r = p; p += (bytes + 255) & ~(size_t)255; return r;
  };
  short* xg      = (short*)alloc((size_t)65536*4096*2);   // 512 MB xg, natural [m][4096]
  short* out0_bf = (short*)alloc((size_t)67108864*2);     // 128 MB layer-0 outputs
  short* x_bf    = (short*)out0_bf;                       // 64 MB alias (dead before out0 written)
  short* wih0_bf = (short*)alloc((size_t)2097152*2);
  short* wih1_bf = (short*)alloc((size_t)4194304*2);
  short* whh0_sw = (short*)alloc((size_t)4194304*2);
  short* whh1_sw = (short*)alloc((size_t)4194304*2);
  int*   flags0  = (int*)alloc((size_t)8*512*32*4);       // fallback flags
  int*   flags1  = (int*)alloc((size_t)8*512*32*4);
  // ring if it fits, else 2-slot ping-pong fallback
  size_t fixed = (size_t)(p - (char*)d_ws);
  bool ring = (fixed + (size_t)512*SLOT) <= ws_size;
  size_t ringbytes = ring ? (size_t)512*SLOT : (size_t)2*SLOT;
  short* hring = (short*)alloc(ringbytes);
  if ((size_t)(p - (char*)d_ws) > ws_size) return;   // cannot even fit fallback — bail

  // ring pre-filled with sentinel (0xFF); fallback flags zeroed only if used
  if (!ring){
    hipMemsetAsync(flags0, 0, (size_t)8*512*32*4, stream);
    hipMemsetAsync(flags1, 0, (size_t)8*512*32*4, stream);
  }
  hipMemsetAsync(hring, 0xFF, ringbytes, stream);

  // converts / weight swizzles
  cvt_bf16<<<33554432/4/256, 256, 0, stream>>>(x,    x_bf,    33554432/4);
  cvt_bf16<<<2097152/4/256,  256, 0, stream>>>(Wih0, wih0_bf, 2097152/4);
  cvt_bf16<<<4194304/4/256,  256, 0, stream>>>(Wih1, wih1_bf, 4194304/4);
  swz_whh <<<524288/256,     256, 0, stream>>>(Whh0, whh0_sw);
  swz_whh <<<524288/256,     256, 0, stream>>>(Whh1, whh1_sw);

  // ---- layer 0 ----
  proj_gemm<512><<<dim3(32, 512), 256, 0, stream>>>(x_bf, wih0_bf, bih0, bhh0, xg);
  if (ring)
    lstm_scan<0, true ><<<dim3(8, 32), 512, 0, stream>>>(hring, whh0_sw, xg,
        omsk, hmsk, cmsk, out0_bf, nullptr, flags0);
  else
    lstm_scan<0, false><<<dim3(8, 32), 512, 0, stream>>>(hring, whh0_sw, xg,
        omsk, hmsk, cmsk, out0_bf, nullptr, flags0);

  // re-sentinel ring for layer 1 (slots must look unwritten again)
  hipMemsetAsync(hring, 0xFF, ringbytes, stream);

  // ---- layer 1 ----
  proj_gemm<1024><<<dim3(32, 512), 256, 0, stream>>>(out0_bf, wih1_bf, bih1, bhh1, xg);
  if (ring)
    lstm_scan<1, true ><<<dim3(8, 32), 512, 0, stream>>>(hring, whh1_sw, xg,
        omsk + 131072, hmsk + 131072, cmsk + 131072, nullptr, out, flags1);
  else
    lstm_scan<1, false><<<dim3(8, 32), 512, 0, stream>>>(hring, whh1_sw, xg,
        omsk + 131072, hmsk + 131072, cmsk + 131072, nullptr, out, flags1);
}

// Round 17
// 3911.734 us; speedup vs baseline: 1.8096x; 1.0463x over previous
//
#include <hip/hip_runtime.h>

// Problem constants
#define B_  128
#define T_  512
#define I_  512
#define H_  1024
#define G4  4096   // 4*H
#define SLOT 262144L   // 256 KB per h slot (B*H*2)
#define SENTW 0xFFFFFFFFu

typedef __attribute__((ext_vector_type(8))) short   short8;
typedef __attribute__((ext_vector_type(4))) short   short4v;
typedef __attribute__((ext_vector_type(4))) float   f32x4;
typedef __attribute__((ext_vector_type(4))) int     int4v;
typedef unsigned long long u64;

__device__ __forceinline__ float bf2f(short u){
  return __uint_as_float(((unsigned)(unsigned short)u) << 16);
}
__device__ __forceinline__ short f2bf(float f){
  unsigned u = __float_as_uint(f);
  unsigned r = (u + 0x7FFFu + ((u >> 16) & 1u)) >> 16;  // RNE
  return (short)r;
}
__device__ __forceinline__ float sigm(float x){ return 1.0f/(1.0f + __expf(-x)); }
__device__ __forceinline__ float tanh_(float x){ return 1.0f - 2.0f/(__expf(2.0f*x) + 1.0f); }
__device__ __forceinline__ bool okq(u64 a){
  return ((unsigned)a != SENTW) & ((unsigned)(a >> 32) != SENTW);
}
__device__ __forceinline__ int okv(int4v c){
  return (c.x != -1) & (c.y != -1) & (c.z != -1) & (c.w != -1);
}

// ---------------- fp32 -> bf16 elementwise convert (vectorized x4) ----------------
__global__ __launch_bounds__(256) void cvt_bf16(const float* __restrict__ in,
                                                short* __restrict__ out, int nq){
  int i = blockIdx.x*256 + threadIdx.x;
  if (i >= nq) return;
  float4 v = ((const float4*)in)[i];
  short4v o; o.x = f2bf(v.x); o.y = f2bf(v.y); o.z = f2bf(v.z); o.w = f2bf(v.w);
  ((short4v*)out)[i] = o;
}

// ---------------- W_hh fp32 [4096][1024] -> bf16 MFMA-fragment-swizzled ----------------
// chunk idx c = (((jb*8 + wv)*2 + ct)*16 + ks)*64 + l ; wv = g*2 + kh.
// Represents W[g*1024 + jb*32 + ct*16 + (l&15)][kh*512 + ks*32 + (l>>4)*8 + e]
__global__ __launch_bounds__(256) void swz_whh(const float* __restrict__ W,
                                               short* __restrict__ out){
  int c = blockIdx.x*256 + threadIdx.x;      // 0 .. 524287
  int l = c & 63, ks = (c >> 6) & 15, ct = (c >> 10) & 1, wvv = (c >> 11) & 7, jb = c >> 14;
  int g = wvv >> 1, kh = wvv & 1;
  long row = (long)(g*1024 + jb*32 + ct*16 + (l & 15));
  int col = kh*512 + ks*32 + (l >> 4)*8;
  const float* src = W + row*H_ + col;
  short8 o;
#pragma unroll
  for (int e = 0; e < 8; ++e) o[e] = f2bf(src[e]);
  ((short8*)out)[c] = o;
}

// ---------------- projection GEMM: C[m,n] = sum_k A[m,k]*W[n,k] + bih[n]+bhh[n] ----------------
// C written NATURAL row-major [m][4096] via LDS-staged coalesced 16B stores.
template<int K>
__global__ __launch_bounds__(256) void proj_gemm(const short* __restrict__ A,
                                                 const short* __restrict__ W,
                                                 const float* __restrict__ bih,
                                                 const float* __restrict__ bhh,
                                                 short* __restrict__ C){
  __shared__ __align__(16) short lds[2][2][128*40];  // tiles; reused as C-stage
  const int tid = threadIdx.x;
  const int l  = tid & 63, wv = tid >> 6;
  const int wm = wv >> 1,  wn = wv & 1;
  const int nt = blockIdx.x, mt = blockIdx.y;
  const int r0 = tid >> 2, cb = (tid & 3) * 8;
  const short* Ab = A + (long)(mt*128 + r0)*K + cb;
  const short* Wb = W + (long)(nt*128 + r0)*K + cb;
  const int lo  = r0*40 + cb;
  const int lo2 = lo + 64*40;
  const int NK = K/32;

  short8 pa0 = *(const short8*)(Ab);
  short8 pa1 = *(const short8*)(Ab + 64*K);
  short8 pb0 = *(const short8*)(Wb);
  short8 pb1 = *(const short8*)(Wb + 64*K);
  *(short8*)&lds[0][0][lo]  = pa0;
  *(short8*)&lds[0][0][lo2] = pa1;
  *(short8*)&lds[0][1][lo]  = pb0;
  *(short8*)&lds[0][1][lo2] = pb1;

  f32x4 acc[4][4];
  f32x4 z = {0.f,0.f,0.f,0.f};
#pragma unroll
  for (int i = 0; i < 4; ++i)
#pragma unroll
    for (int j = 0; j < 4; ++j) acc[i][j] = z;

  for (int kt = 0; kt < NK; ++kt){
    __syncthreads();
    if (kt + 1 < NK){
      pa0 = *(const short8*)(Ab + (kt+1)*32);
      pa1 = *(const short8*)(Ab + (kt+1)*32 + 64*K);
      pb0 = *(const short8*)(Wb + (kt+1)*32);
      pb1 = *(const short8*)(Wb + (kt+1)*32 + 64*K);
    }
    const short* As = lds[kt & 1][0];
    const short* Bs = lds[kt & 1][1];
    short8 bfr[4];
#pragma unroll
    for (int nf = 0; nf < 4; ++nf)
      bfr[nf] = *(const short8*)&Bs[(wn*64 + nf*16 + (l & 15))*40 + (l >> 4)*8];
#pragma unroll
    for (int mf = 0; mf < 4; ++mf){
      short8 af = *(const short8*)&As[(wm*64 + mf*16 + (l & 15))*40 + (l >> 4)*8];
#pragma unroll
      for (int nf = 0; nf < 4; ++nf)
        acc[mf][nf] = __builtin_amdgcn_mfma_f32_16x16x32_bf16(af, bfr[nf], acc[mf][nf], 0, 0, 0);
    }
    if (kt + 1 < NK){
      int nb = (kt + 1) & 1;
      *(short8*)&lds[nb][0][lo]  = pa0;
      *(short8*)&lds[nb][0][lo2] = pa1;
      *(short8*)&lds[nb][1][lo]  = pb0;
      *(short8*)&lds[nb][1][lo2] = pb1;
    }
  }

  // ---- staged epilogue: bias + bf16 into LDS [128][132-padded], then 16B stores ----
  __syncthreads();                               // all MFMA-phase ds_reads done
  short* cst = (short*)&lds[0][0][0];            // 128*132 shorts = 33792 B (fits 40960)
#pragma unroll
  for (int nf = 0; nf < 4; ++nf){
    int nc = wn*64 + nf*16 + (l & 15);
    int n  = nt*128 + nc;
    float bs = bih[n] + bhh[n];
#pragma unroll
    for (int mf = 0; mf < 4; ++mf){
#pragma unroll
      for (int r = 0; r < 4; ++r){
        int mr = wm*64 + mf*16 + (l >> 4)*4 + r;   // C/D: row=(l>>4)*4+r, col=l&15
        cst[mr*132 + nc] = f2bf(acc[mf][nf][r] + bs);
      }
    }
  }
  __syncthreads();
  const long m0 = (long)mt*128;
  const int  n0 = nt*128;
#pragma unroll
  for (int i = 0; i < 8; ++i){
    int sid = i*256 + tid;
    int mr = sid >> 4, seg = sid & 15;
    *(short8*)&C[(m0 + mr)*G4 + n0 + seg*8] = *(const short8*)&cst[mr*132 + seg*8];
  }
}

// ---------------- persistent LSTM scan (one launch per layer) ----------------
// grid (bt=8, jb=32) = 256 blocks x 512 thr; 1 block/CU. Group bt = 32 blocks.
// Wave wv = g*2 + kh; W = 32 frags (128 regs), pinned. SENTINEL PROTOCOL (RING,
// R12/R14-proven) + HYBRID GATHER (new): ring pre-filled 0xFF (bf16 NaN,
// unreachable by f2bf of finite h). Producer: pack (wave-local LDS) -> 8x
// dwordx4 sc1 fire-and-forget. Consumer: first-touch each chunk with a PLAIN
// cacheable dwordx4 — slots are WRITE-ONCE, so any non-sentinel value from any
// path IS the true data (staleness can only show the older value = sentinel);
// same-XCD blocks share one L2 fill (MALL reads /8, transactions /8). Chunks
// that return sentinel dwords fall into the R12-proven agent-atomic retry loop
// (bypasses the stale cached line — R13's failure mode, handled not fatal).
// Deadlock-free: producers never wait. Fallback (!RING): flags + agent 2-slot.
// xg NATURAL row-major [m][4096].
//
// h slot layout: chunk (X = jb*64 + l') holds h[bt*16 + (l'&15)]
//   [jb*32 + (l'>>4)*8 + e]. Consumer wave (g,kh): a[ks] = chunk[(kh*16+ks)*64 + l].
// EW thread map: idx = wv*8 + (l>>3); bl = idx&15; jl = (idx>>4)*8 + (l&7).
template<int LAYER, bool RING>
__global__ __launch_bounds__(512, 2) void lstm_scan(
    short* __restrict__ hring,
    const short* __restrict__ Wsw, const short* __restrict__ xg,
    const float* __restrict__ om, const float* __restrict__ hm, const float* __restrict__ cm,
    short* __restrict__ out0, float* __restrict__ dout,
    int* __restrict__ flags)     // fallback only: [8 bt][512 t][32 jb], pre-zeroed
{
  const int tid = threadIdx.x;
  const int l = tid & 63, wv = tid >> 6;
  const int bt = blockIdx.x, jb = blockIdx.y;

  // ---- load W fragments once; pin in registers ----
  short8 w0[16], w1[16];
  {
    const short8* wp = (const short8*)Wsw + ((long)((jb*8 + wv)*2)*16)*64 + l;
#pragma unroll
    for (int ks = 0; ks < 16; ++ks) w0[ks] = wp[ks*64];
#pragma unroll
    for (int ks = 0; ks < 16; ++ks) w1[ks] = wp[(16 + ks)*64];
    f32x4* wf0 = (f32x4*)w0;
    f32x4* wf1 = (f32x4*)w1;
#pragma unroll
    for (int i = 0; i < 16; ++i){ asm volatile("" : "+v"(wf0[i])); asm volatile("" : "+v"(wf1[i])); }
  }

  // ---- EW thread map (chunk-aligned): idx = wv*8 + (l>>3) ----
  const int idx = wv*8 + (l >> 3);
  const int bl  = idx & 15;
  const int jl  = ((idx >> 4) << 3) + (l & 7);
  const int jcol = jb*32 + jl;
  const long bj = (long)(bt*16 + bl)*H_ + jcol;
  const float mo = om[bj], mh = hm[bj], mc = cm[bj];
  float c = 0.f;
  const int ct_r = jl >> 4;                          // col-tile of my jl
  const int lane_src = (jl & 15) + ((bl >> 2) << 4); // lane holding (bl, jl)
  const int rr = bl & 3;
  const int kh = wv & 1;

  __shared__ __align__(16) short hbuf[2048*8];    // 32KB staged group h
  __shared__ float red[16*264];                   // [wv*2+ct][lane*4+r], padded
  __shared__ __align__(16) short sstage[512];     // wave-local pack staging
  int* flbase = flags + (long)bt*T_*32;

  // per-thread gather offsets (chunk index within slot's bt region)
  const int ch0 = wv*256 +   0 + l;
  const int ch1 = wv*256 +  64 + l;
  const int ch2 = wv*256 + 128 + l;
  const int ch3 = wv*256 + 192 + l;

  // xg natural layout: element base for this thread (+ t*G4 + g*H_)
  const long xbase = (long)(bt*16 + bl)*T_*G4 + jcol;
  short xv0 = xg[xbase], xv1 = xg[xbase + H_], xv2 = xg[xbase + 2*H_], xv3 = xg[xbase + 3*H_];

  for (int t = 0; t < T_; ++t){
    const long slotoff  = RING ? (long)t*SLOT     : (long)(t & 1)*SLOT;
    const long nslotoff = RING ? (long)(t+1)*SLOT : (long)((t+1) & 1)*SLOT;

    if (t > 0){
      const char* hb = (const char*)hring + slotoff + (long)bt*32768;
      if constexpr (RING){
        // ---- hybrid sentinel gather ----
        // 1) plain cacheable first touch (write-once => non-sentinel == data;
        //    same-XCD blocks share the L2 fill)
        int4v c0 = *(const int4v*)(hb + (long)ch0*16);
        int4v c1 = *(const int4v*)(hb + (long)ch1*16);
        int4v c2 = *(const int4v*)(hb + (long)ch2*16);
        int4v c3 = *(const int4v*)(hb + (long)ch3*16);
        int ok = 0;
        if (okv(c0)){ *(int4v*)&hbuf[ch0*8] = c0; ok |= 1; }
        if (okv(c1)){ *(int4v*)&hbuf[ch1*8] = c1; ok |= 2; }
        if (okv(c2)){ *(int4v*)&hbuf[ch2*8] = c2; ok |= 4; }
        if (okv(c3)){ *(int4v*)&hbuf[ch3*8] = c3; ok |= 8; }
        // 2) agent-atomic retry for late chunks (bypasses stale cached lines)
        if (ok != 15){
          const u64* hp = (const u64*)hb;
          int spins = 0;
          while (true){
            if (!(ok & 1)){
              u64 a = __hip_atomic_load(hp + (long)ch0*2,     __ATOMIC_RELAXED, __HIP_MEMORY_SCOPE_AGENT);
              u64 b = __hip_atomic_load(hp + (long)ch0*2 + 1, __ATOMIC_RELAXED, __HIP_MEMORY_SCOPE_AGENT);
              if (okq(a) & okq(b)){ u64* d = (u64*)&hbuf[ch0*8]; d[0] = a; d[1] = b; ok |= 1; }
            }
            if (!(ok & 2)){
              u64 a = __hip_atomic_load(hp + (long)ch1*2,     __ATOMIC_RELAXED, __HIP_MEMORY_SCOPE_AGENT);
              u64 b = __hip_atomic_load(hp + (long)ch1*2 + 1, __ATOMIC_RELAXED, __HIP_MEMORY_SCOPE_AGENT);
              if (okq(a) & okq(b)){ u64* d = (u64*)&hbuf[ch1*8]; d[0] = a; d[1] = b; ok |= 2; }
            }
            if (!(ok & 4)){
              u64 a = __hip_atomic_load(hp + (long)ch2*2,     __ATOMIC_RELAXED, __HIP_MEMORY_SCOPE_AGENT);
              u64 b = __hip_atomic_load(hp + (long)ch2*2 + 1, __ATOMIC_RELAXED, __HIP_MEMORY_SCOPE_AGENT);
              if (okq(a) & okq(b)){ u64* d = (u64*)&hbuf[ch2*8]; d[0] = a; d[1] = b; ok |= 4; }
            }
            if (!(ok & 8)){
              u64 a = __hip_atomic_load(hp + (long)ch3*2,     __ATOMIC_RELAXED, __HIP_MEMORY_SCOPE_AGENT);
              u64 b = __hip_atomic_load(hp + (long)ch3*2 + 1, __ATOMIC_RELAXED, __HIP_MEMORY_SCOPE_AGENT);
              if (okq(a) & okq(b)){ u64* d = (u64*)&hbuf[ch3*8]; d[0] = a; d[1] = b; ok |= 8; }
            }
            if (ok == 15) break;
            if (++spins > (1 << 20)) break;   // safety: wrong-answer instead of hang
            if (spins > 2) __builtin_amdgcn_s_sleep(2);
          }
        }
      } else {
        // fallback: flag-gated agent gather (R11)
        const u64* hp = (const u64*)hb;
        short8 vv[4];
#pragma unroll
        for (int i = 0; i < 4; ++i){
          const u64* ap = hp + (long)(wv*256 + i*64 + l)*2;
          union { u64 q[2]; short8 s; } uu;
          uu.q[0] = __hip_atomic_load(ap,     __ATOMIC_RELAXED, __HIP_MEMORY_SCOPE_AGENT);
          uu.q[1] = __hip_atomic_load(ap + 1, __ATOMIC_RELAXED, __HIP_MEMORY_SCOPE_AGENT);
          vv[i] = uu.s;
        }
#pragma unroll
        for (int i = 0; i < 4; ++i)
          *(short8*)&hbuf[(wv*256 + i*64 + l)*8] = vv[i];
      }
      __syncthreads();

      // ---- 32 MFMA: 2 col-tiles x 16 ks (own K-half only), 4 acc chains ----
      f32x4 a00 = {0.f,0.f,0.f,0.f}, a01 = {0.f,0.f,0.f,0.f};
      f32x4 a10 = {0.f,0.f,0.f,0.f}, a11 = {0.f,0.f,0.f,0.f};
#pragma unroll
      for (int ks = 0; ks < 16; ++ks){
        short8 av = *(const short8*)&hbuf[((kh*16 + ks)*64 + l)*8];
        if (ks & 1){
          a01 = __builtin_amdgcn_mfma_f32_16x16x32_bf16(av, w0[ks], a01, 0, 0, 0);
          a11 = __builtin_amdgcn_mfma_f32_16x16x32_bf16(av, w1[ks], a11, 0, 0, 0);
        } else {
          a00 = __builtin_amdgcn_mfma_f32_16x16x32_bf16(av, w0[ks], a00, 0, 0, 0);
          a10 = __builtin_amdgcn_mfma_f32_16x16x32_bf16(av, w1[ks], a10, 0, 0, 0);
        }
      }
      f32x4 s0, s1;
#pragma unroll
      for (int r = 0; r < 4; ++r){ s0[r] = a00[r] + a01[r]; s1[r] = a10[r] + a11[r]; }
      *(f32x4*)&red[(wv*2 + 0)*264 + l*4] = s0;
      *(f32x4*)&red[(wv*2 + 1)*264 + l*4] = s1;
      __syncthreads();
    }

    // ---- elementwise (thread owns (bl, jl)) ----
    float gate[4];
    short xvv[4] = {xv0, xv1, xv2, xv3};
#pragma unroll
    for (int g = 0; g < 4; ++g){
      float rv = 0.f;
      if (t > 0){
        rv = red[((g*2 + 0)*2 + ct_r)*264 + lane_src*4 + rr]
           + red[((g*2 + 1)*2 + ct_r)*264 + lane_src*4 + rr];
      }
      gate[g] = rv + bf2f(xvv[g]);
    }
    float ii = sigm(gate[0]);
    float ff = sigm(gate[1]);
    float gg = tanh_(gate[2]);
    float oo = sigm(gate[3]);
    float c2 = ff*c + ii*gg;
    float h2 = oo*tanh_(c2);
    c = c2*mc;
    float hn = h2*mh;

    if (t == T_ - 1){
      if (LAYER == 0){
        out0[((long)(bt*16 + bl)*T_ + t)*H_ + jcol] = f2bf(h2*mo);
      } else {
        dout[((long)(bt*16 + bl)*T_ + t)*H_ + jcol] = h2*mo;
        dout[(long)B_*T_*H_ + bj] = hn;                    // hf
        dout[(long)B_*T_*H_ + (long)B_*H_ + bj] = c;       // cf
      }
      break;
    }

    // ---- wave-local pack: lane l -> sstage[wv*64+l]; lanes<8 store chunks ----
    sstage[wv*64 + l] = f2bf(hn);
    asm volatile("s_waitcnt lgkmcnt(0)" ::: "memory");   // own wave's ds_write done
    __builtin_amdgcn_sched_barrier(0);
    if (l < 8){
      short8 pk = *(const short8*)&sstage[wv*64 + l*8];
      char* hdst = (char*)hring + nslotoff
                 + ((long)bt*2048 + jb*64 + wv*8 + l)*16;
      if constexpr (RING){
        // fire-and-forget: sentinel protocol needs no ack
        asm volatile("global_store_dwordx4 %0, %1, off sc1" :: "v"(hdst), "v"(pk) : "memory");
      } else {
        union { short8 s; u64 q[2]; } uu; uu.s = pk;
        u64* qp = (u64*)hdst;
        __hip_atomic_store(qp,     uu.q[0], __ATOMIC_RELAXED, __HIP_MEMORY_SCOPE_AGENT);
        __hip_atomic_store(qp + 1, uu.q[1], __ATOMIC_RELAXED, __HIP_MEMORY_SCOPE_AGENT);
      }
    }
    if constexpr (!RING){
      asm volatile("s_waitcnt vmcnt(0)" ::: "memory");   // h at coherence point
      __syncthreads();
      if (tid == 0)
        __hip_atomic_store(&flbase[(long)t*32 + jb], 1,
                           __ATOMIC_RELAXED, __HIP_MEMORY_SCOPE_AGENT);
    }

    // ---- out stores + xg prefetch (overlap next-step poll/gather) ----
    if (LAYER == 0){
      out0[((long)(bt*16 + bl)*T_ + t)*H_ + jcol] = f2bf(h2*mo);
    } else {
      dout[((long)(bt*16 + bl)*T_ + t)*H_ + jcol] = h2*mo;
    }
    {
      const short* xp = xg + xbase + (long)(t + 1)*G4;
      xv0 = xp[0]; xv1 = xp[H_]; xv2 = xp[2*H_]; xv3 = xp[3*H_];
    }

    if constexpr (!RING){
      // fallback: poll 32 packed flags (16 lanes x u64)
      const u64* fp = (const u64*)&flbase[(long)t*32];
      int spins = 0;
      while (true){
        int ok = 1;
        if (l < 16){
          u64 v = __hip_atomic_load(fp + l, __ATOMIC_RELAXED, __HIP_MEMORY_SCOPE_AGENT);
          ok = ((unsigned)v != 0u) & ((unsigned)(v >> 32) != 0u);
        }
        if (__all(ok)) break;
        if (++spins > (1 << 20)) break;
        if (spins > 8) __builtin_amdgcn_s_sleep(1);
      }
      __builtin_amdgcn_sched_barrier(0);
      __builtin_amdgcn_fence(__ATOMIC_ACQUIRE, "workgroup");
    }
  }
}

extern "C" void kernel_launch(void* const* d_in, const int* in_sizes, int n_in,
                              void* d_out, int out_size, void* d_ws, size_t ws_size,
                              hipStream_t stream){
  const float* x    = (const float*)d_in[0];
  const float* Wih0 = (const float*)d_in[1];
  const float* Whh0 = (const float*)d_in[2];
  const float* bih0 = (const float*)d_in[3];
  const float* bhh0 = (const float*)d_in[4];
  const float* Wih1 = (const float*)d_in[5];
  const float* Whh1 = (const float*)d_in[6];
  const float* bih1 = (const float*)d_in[7];
  const float* bhh1 = (const float*)d_in[8];
  const float* omsk = (const float*)d_in[9];
  const float* hmsk = (const float*)d_in[10];
  const float* cmsk = (const float*)d_in[11];
  float* out = (float*)d_out;

  char* p = (char*)d_ws;
  auto alloc = [&](size_t bytes)->char*{
    char* r = p; p += (bytes + 255) & ~(size_t)255; return r;
  };
  short* xg      = (short*)alloc((size_t)65536*4096*2);   // 512 MB xg, natural [m][4096]
  short* out0_bf = (short*)alloc((size_t)67108864*2);     // 128 MB layer-0 outputs
  short* x_bf    = (short*)out0_bf;                       // 64 MB alias (dead before out0 written)
  short* wih0_bf = (short*)alloc((size_t)2097152*2);
  short* wih1_bf = (short*)alloc((size_t)4194304*2);
  short* whh0_sw = (short*)alloc((size_t)4194304*2);
  short* whh1_sw = (short*)alloc((size_t)4194304*2);
  int*   flags0  = (int*)alloc((size_t)8*512*32*4);       // fallback flags
  int*   flags1  = (int*)alloc((size_t)8*512*32*4);
  // ring if it fits, else 2-slot ping-pong fallback
  size_t fixed = (size_t)(p - (char*)d_ws);
  bool ring = (fixed + (size_t)512*SLOT) <= ws_size;
  size_t ringbytes = ring ? (size_t)512*SLOT : (size_t)2*SLOT;
  short* hring = (short*)alloc(ringbytes);
  if ((size_t)(p - (char*)d_ws) > ws_size) return;   // cannot even fit fallback — bail

  // ring pre-filled with sentinel (0xFF); fallback flags zeroed only if used
  if (!ring){
    hipMemsetAsync(flags0, 0, (size_t)8*512*32*4, stream);
    hipMemsetAsync(flags1, 0, (size_t)8*512*32*4, stream);
  }
  hipMemsetAsync(hring, 0xFF, ringbytes, stream);

  // converts / weight swizzles
  cvt_bf16<<<33554432/4/256, 256, 0, stream>>>(x,    x_bf,    33554432/4);
  cvt_bf16<<<2097152/4/256,  256, 0, stream>>>(Wih0, wih0_bf, 2097152/4);
  cvt_bf16<<<4194304/4/256,  256, 0, stream>>>(Wih1, wih1_bf, 4194304/4);
  swz_whh <<<524288/256,     256, 0, stream>>>(Whh0, whh0_sw);
  swz_whh <<<524288/256,     256, 0, stream>>>(Whh1, whh1_sw);

  // ---- layer 0 ----
  proj_gemm<512><<<dim3(32, 512), 256, 0, stream>>>(x_bf, wih0_bf, bih0, bhh0, xg);
  if (ring)
    lstm_scan<0, true ><<<dim3(8, 32), 512, 0, stream>>>(hring, whh0_sw, xg,
        omsk, hmsk, cmsk, out0_bf, nullptr, flags0);
  else
    lstm_scan<0, false><<<dim3(8, 32), 512, 0, stream>>>(hring, whh0_sw, xg,
        omsk, hmsk, cmsk, out0_bf, nullptr, flags0);

  // re-sentinel ring for layer 1 (slots must look unwritten again)
  hipMemsetAsync(hring, 0xFF, ringbytes, stream);

  // ---- layer 1 ----
  proj_gemm<1024><<<dim3(32, 512), 256, 0, stream>>>(out0_bf, wih1_bf, bih1, bhh1, xg);
  if (ring)
    lstm_scan<1, true ><<<dim3(8, 32), 512, 0, stream>>>(hring, whh1_sw, xg,
        omsk + 131072, hmsk + 131072, cmsk + 131072, nullptr, out, flags1);
  else
    lstm_scan<1, false><<<dim3(8, 32), 512, 0, stream>>>(hring, whh1_sw, xg,
        omsk + 131072, hmsk + 131072, cmsk + 131072, nullptr, out, flags1);
}

// Round 18
// 3820.384 us; speedup vs baseline: 1.8529x; 1.0239x over previous
//
#include <hip/hip_runtime.h>

// Problem constants
#define B_  128
#define T_  512
#define I_  512
#define H_  1024
#define G4  4096   // 4*H
#define SLOT 262144L   // 256 KB per h slot (B*H*2)
#define SENTW 0xFFFFFFFFu

typedef __attribute__((ext_vector_type(8))) short   short8;
typedef __attribute__((ext_vector_type(4))) short   short4v;
typedef __attribute__((ext_vector_type(4))) float   f32x4;
typedef __attribute__((ext_vector_type(4))) int     int4v;
typedef unsigned long long u64;

__device__ __forceinline__ float bf2f(short u){
  return __uint_as_float(((unsigned)(unsigned short)u) << 16);
}
__device__ __forceinline__ short f2bf(float f){
  unsigned u = __float_as_uint(f);
  unsigned r = (u + 0x7FFFu + ((u >> 16) & 1u)) >> 16;  // RNE
  return (short)r;
}
__device__ __forceinline__ float sigm(float x){ return 1.0f/(1.0f + __expf(-x)); }
__device__ __forceinline__ float tanh_(float x){ return 1.0f - 2.0f/(__expf(2.0f*x) + 1.0f); }
__device__ __forceinline__ bool okq(u64 a){
  return ((unsigned)a != SENTW) & ((unsigned)(a >> 32) != SENTW);
}
__device__ __forceinline__ int okv(int4v c){
  return (c.x != -1) & (c.y != -1) & (c.z != -1) & (c.w != -1);
}
// async global->LDS, 16B per lane; LDS dest = wave-uniform base + lane*16
__device__ __forceinline__ void ldst16(const short* g, short* lp){
  __builtin_amdgcn_global_load_lds(
      (const __attribute__((address_space(1))) void*)g,
      (__attribute__((address_space(3))) void*)lp, 16, 0, 0);
}

// ---------------- fp32 -> bf16 elementwise convert (vectorized x4) ----------------
__global__ __launch_bounds__(256) void cvt_bf16(const float* __restrict__ in,
                                                short* __restrict__ out, int nq){
  int i = blockIdx.x*256 + threadIdx.x;
  if (i >= nq) return;
  float4 v = ((const float4*)in)[i];
  short4v o; o.x = f2bf(v.x); o.y = f2bf(v.y); o.z = f2bf(v.z); o.w = f2bf(v.w);
  ((short4v*)out)[i] = o;
}

// ---------------- W_hh fp32 [4096][1024] -> bf16 MFMA-fragment-swizzled ----------------
// chunk idx c = (((jb*8 + wv)*2 + ct)*16 + ks)*64 + l ; wv = g*2 + kh.
// Represents W[g*1024 + jb*32 + ct*16 + (l&15)][kh*512 + ks*32 + (l>>4)*8 + e]
__global__ __launch_bounds__(256) void swz_whh(const float* __restrict__ W,
                                               short* __restrict__ out){
  int c = blockIdx.x*256 + threadIdx.x;      // 0 .. 524287
  int l = c & 63, ks = (c >> 6) & 15, ct = (c >> 10) & 1, wvv = (c >> 11) & 7, jb = c >> 14;
  int g = wvv >> 1, kh = wvv & 1;
  long row = (long)(g*1024 + jb*32 + ct*16 + (l & 15));
  int col = kh*512 + ks*32 + (l >> 4)*8;
  const float* src = W + row*H_ + col;
  short8 o;
#pragma unroll
  for (int e = 0; e < 8; ++e) o[e] = f2bf(src[e]);
  ((short8*)out)[c] = o;
}

// ---------------- projection GEMM: C[m,n] = sum_k A[m,k]*W[n,k] + bih[n]+bhh[n] ----------------
// m97-style: global_load_lds width=16 staging into linear [128][32] LDS tiles,
// double-buffered; barrier drains the async queue (m97 schedule, 874 TF class).
// C written NATURAL row-major [m][4096] via LDS-staged coalesced 16B stores.
template<int K>
__global__ __launch_bounds__(256) void proj_gemm(const short* __restrict__ A,
                                                 const short* __restrict__ W,
                                                 const float* __restrict__ bih,
                                                 const float* __restrict__ bhh,
                                                 short* __restrict__ C){
  __shared__ __align__(16) short sh[16896];  // [2][A:4096|B:4096] tiles; reused as C-stage
  const int tid = threadIdx.x;
  const int l  = tid & 63, wv = tid >> 6;
  const int wm = wv >> 1,  wn = wv & 1;
  const int nt = blockIdx.x, mt = blockIdx.y;
  const int NK = K/32;

  // per-lane global src (lane l stages 16B of tile row srow+j*16, col-chunk l&3)
  const int srow = wv*32 + (l >> 2);
  const int scol = (l & 3)*8;
  const short* Ag = A + (long)(mt*128 + srow)*K + scol;
  const short* Wg = W + (long)(nt*128 + srow)*K + scol;

  auto stage = [&](int buf, int kt){
#pragma unroll
    for (int j = 0; j < 2; ++j){
      short* la = &sh[buf*8192 +        (wv*32 + j*16)*32];   // wave-uniform base
      short* lb = &sh[buf*8192 + 4096 + (wv*32 + j*16)*32];
      ldst16(Ag + (long)(j*16)*K + kt*32, la);
      ldst16(Wg + (long)(j*16)*K + kt*32, lb);
    }
  };

  stage(0, 0);

  f32x4 acc[4][4];
  f32x4 z = {0.f,0.f,0.f,0.f};
#pragma unroll
  for (int i = 0; i < 4; ++i)
#pragma unroll
    for (int j = 0; j < 4; ++j) acc[i][j] = z;

  for (int kt = 0; kt < NK; ++kt){
    __syncthreads();                     // drains async loads of buf kt&1 (vmcnt+lgkm)
    if (kt + 1 < NK) stage((kt + 1) & 1, kt + 1);
    const short* As = &sh[(kt & 1)*8192];
    const short* Bs = &sh[(kt & 1)*8192 + 4096];
    short8 bfr[4];
#pragma unroll
    for (int nf = 0; nf < 4; ++nf)
      bfr[nf] = *(const short8*)&Bs[(wn*64 + nf*16 + (l & 15))*32 + (l >> 4)*8];
#pragma unroll
    for (int mf = 0; mf < 4; ++mf){
      short8 af = *(const short8*)&As[(wm*64 + mf*16 + (l & 15))*32 + (l >> 4)*8];
#pragma unroll
      for (int nf = 0; nf < 4; ++nf)
        acc[mf][nf] = __builtin_amdgcn_mfma_f32_16x16x32_bf16(af, bfr[nf], acc[mf][nf], 0, 0, 0);
    }
  }

  // ---- staged epilogue: bias + bf16 into LDS [128][132-padded], then 16B stores ----
  __syncthreads();                               // all MFMA-phase ds_reads done
  short* cst = sh;                               // 128*132 = 16896 shorts exactly
#pragma unroll
  for (int nf = 0; nf < 4; ++nf){
    int nc = wn*64 + nf*16 + (l & 15);
    int n  = nt*128 + nc;
    float bs = bih[n] + bhh[n];
#pragma unroll
    for (int mf = 0; mf < 4; ++mf){
#pragma unroll
      for (int r = 0; r < 4; ++r){
        int mr = wm*64 + mf*16 + (l >> 4)*4 + r;   // C/D: row=(l>>4)*4+r, col=l&15
        cst[mr*132 + nc] = f2bf(acc[mf][nf][r] + bs);
      }
    }
  }
  __syncthreads();
  const long m0 = (long)mt*128;
  const int  n0 = nt*128;
#pragma unroll
  for (int i = 0; i < 8; ++i){
    int sid = i*256 + tid;
    int mr = sid >> 4, seg = sid & 15;
    *(short8*)&C[(m0 + mr)*G4 + n0 + seg*8] = *(const short8*)&cst[mr*132 + seg*8];
  }
}

// ---------------- persistent LSTM scan (one launch per layer) ----------------
// BYTE-IDENTICAL to R17 (proven): sentinel ring + hybrid gather (plain-first
// cacheable dwordx4, agent-atomic retry for late chunks). See R17 notes.
template<int LAYER, bool RING>
__global__ __launch_bounds__(512, 2) void lstm_scan(
    short* __restrict__ hring,
    const short* __restrict__ Wsw, const short* __restrict__ xg,
    const float* __restrict__ om, const float* __restrict__ hm, const float* __restrict__ cm,
    short* __restrict__ out0, float* __restrict__ dout,
    int* __restrict__ flags)     // fallback only: [8 bt][512 t][32 jb], pre-zeroed
{
  const int tid = threadIdx.x;
  const int l = tid & 63, wv = tid >> 6;
  const int bt = blockIdx.x, jb = blockIdx.y;

  // ---- load W fragments once; pin in registers ----
  short8 w0[16], w1[16];
  {
    const short8* wp = (const short8*)Wsw + ((long)((jb*8 + wv)*2)*16)*64 + l;
#pragma unroll
    for (int ks = 0; ks < 16; ++ks) w0[ks] = wp[ks*64];
#pragma unroll
    for (int ks = 0; ks < 16; ++ks) w1[ks] = wp[(16 + ks)*64];
    f32x4* wf0 = (f32x4*)w0;
    f32x4* wf1 = (f32x4*)w1;
#pragma unroll
    for (int i = 0; i < 16; ++i){ asm volatile("" : "+v"(wf0[i])); asm volatile("" : "+v"(wf1[i])); }
  }

  // ---- EW thread map (chunk-aligned): idx = wv*8 + (l>>3) ----
  const int idx = wv*8 + (l >> 3);
  const int bl  = idx & 15;
  const int jl  = ((idx >> 4) << 3) + (l & 7);
  const int jcol = jb*32 + jl;
  const long bj = (long)(bt*16 + bl)*H_ + jcol;
  const float mo = om[bj], mh = hm[bj], mc = cm[bj];
  float c = 0.f;
  const int ct_r = jl >> 4;                          // col-tile of my jl
  const int lane_src = (jl & 15) + ((bl >> 2) << 4); // lane holding (bl, jl)
  const int rr = bl & 3;
  const int kh = wv & 1;

  __shared__ __align__(16) short hbuf[2048*8];    // 32KB staged group h
  __shared__ float red[16*264];                   // [wv*2+ct][lane*4+r], padded
  __shared__ __align__(16) short sstage[512];     // wave-local pack staging
  int* flbase = flags + (long)bt*T_*32;

  // per-thread gather offsets (chunk index within slot's bt region)
  const int ch0 = wv*256 +   0 + l;
  const int ch1 = wv*256 +  64 + l;
  const int ch2 = wv*256 + 128 + l;
  const int ch3 = wv*256 + 192 + l;

  // xg natural layout: element base for this thread (+ t*G4 + g*H_)
  const long xbase = (long)(bt*16 + bl)*T_*G4 + jcol;
  short xv0 = xg[xbase], xv1 = xg[xbase + H_], xv2 = xg[xbase + 2*H_], xv3 = xg[xbase + 3*H_];

  for (int t = 0; t < T_; ++t){
    const long slotoff  = RING ? (long)t*SLOT     : (long)(t & 1)*SLOT;
    const long nslotoff = RING ? (long)(t+1)*SLOT : (long)((t+1) & 1)*SLOT;

    if (t > 0){
      const char* hb = (const char*)hring + slotoff + (long)bt*32768;
      if constexpr (RING){
        // ---- hybrid sentinel gather ----
        int4v c0 = *(const int4v*)(hb + (long)ch0*16);
        int4v c1 = *(const int4v*)(hb + (long)ch1*16);
        int4v c2 = *(const int4v*)(hb + (long)ch2*16);
        int4v c3 = *(const int4v*)(hb + (long)ch3*16);
        int ok = 0;
        if (okv(c0)){ *(int4v*)&hbuf[ch0*8] = c0; ok |= 1; }
        if (okv(c1)){ *(int4v*)&hbuf[ch1*8] = c1; ok |= 2; }
        if (okv(c2)){ *(int4v*)&hbuf[ch2*8] = c2; ok |= 4; }
        if (okv(c3)){ *(int4v*)&hbuf[ch3*8] = c3; ok |= 8; }
        if (ok != 15){
          const u64* hp = (const u64*)hb;
          int spins = 0;
          while (true){
            if (!(ok & 1)){
              u64 a = __hip_atomic_load(hp + (long)ch0*2,     __ATOMIC_RELAXED, __HIP_MEMORY_SCOPE_AGENT);
              u64 b = __hip_atomic_load(hp + (long)ch0*2 + 1, __ATOMIC_RELAXED, __HIP_MEMORY_SCOPE_AGENT);
              if (okq(a) & okq(b)){ u64* d = (u64*)&hbuf[ch0*8]; d[0] = a; d[1] = b; ok |= 1; }
            }
            if (!(ok & 2)){
              u64 a = __hip_atomic_load(hp + (long)ch1*2,     __ATOMIC_RELAXED, __HIP_MEMORY_SCOPE_AGENT);
              u64 b = __hip_atomic_load(hp + (long)ch1*2 + 1, __ATOMIC_RELAXED, __HIP_MEMORY_SCOPE_AGENT);
              if (okq(a) & okq(b)){ u64* d = (u64*)&hbuf[ch1*8]; d[0] = a; d[1] = b; ok |= 2; }
            }
            if (!(ok & 4)){
              u64 a = __hip_atomic_load(hp + (long)ch2*2,     __ATOMIC_RELAXED, __HIP_MEMORY_SCOPE_AGENT);
              u64 b = __hip_atomic_load(hp + (long)ch2*2 + 1, __ATOMIC_RELAXED, __HIP_MEMORY_SCOPE_AGENT);
              if (okq(a) & okq(b)){ u64* d = (u64*)&hbuf[ch2*8]; d[0] = a; d[1] = b; ok |= 4; }
            }
            if (!(ok & 8)){
              u64 a = __hip_atomic_load(hp + (long)ch3*2,     __ATOMIC_RELAXED, __HIP_MEMORY_SCOPE_AGENT);
              u64 b = __hip_atomic_load(hp + (long)ch3*2 + 1, __ATOMIC_RELAXED, __HIP_MEMORY_SCOPE_AGENT);
              if (okq(a) & okq(b)){ u64* d = (u64*)&hbuf[ch3*8]; d[0] = a; d[1] = b; ok |= 8; }
            }
            if (ok == 15) break;
            if (++spins > (1 << 20)) break;   // safety: wrong-answer instead of hang
            if (spins > 2) __builtin_amdgcn_s_sleep(2);
          }
        }
      } else {
        // fallback: flag-gated agent gather (R11)
        const u64* hp = (const u64*)hb;
        short8 vv[4];
#pragma unroll
        for (int i = 0; i < 4; ++i){
          const u64* ap = hp + (long)(wv*256 + i*64 + l)*2;
          union { u64 q[2]; short8 s; } uu;
          uu.q[0] = __hip_atomic_load(ap,     __ATOMIC_RELAXED, __HIP_MEMORY_SCOPE_AGENT);
          uu.q[1] = __hip_atomic_load(ap + 1, __ATOMIC_RELAXED, __HIP_MEMORY_SCOPE_AGENT);
          vv[i] = uu.s;
        }
#pragma unroll
        for (int i = 0; i < 4; ++i)
          *(short8*)&hbuf[(wv*256 + i*64 + l)*8] = vv[i];
      }
      __syncthreads();

      // ---- 32 MFMA: 2 col-tiles x 16 ks (own K-half only), 4 acc chains ----
      f32x4 a00 = {0.f,0.f,0.f,0.f}, a01 = {0.f,0.f,0.f,0.f};
      f32x4 a10 = {0.f,0.f,0.f,0.f}, a11 = {0.f,0.f,0.f,0.f};
#pragma unroll
      for (int ks = 0; ks < 16; ++ks){
        short8 av = *(const short8*)&hbuf[((kh*16 + ks)*64 + l)*8];
        if (ks & 1){
          a01 = __builtin_amdgcn_mfma_f32_16x16x32_bf16(av, w0[ks], a01, 0, 0, 0);
          a11 = __builtin_amdgcn_mfma_f32_16x16x32_bf16(av, w1[ks], a11, 0, 0, 0);
        } else {
          a00 = __builtin_amdgcn_mfma_f32_16x16x32_bf16(av, w0[ks], a00, 0, 0, 0);
          a10 = __builtin_amdgcn_mfma_f32_16x16x32_bf16(av, w1[ks], a10, 0, 0, 0);
        }
      }
      f32x4 s0, s1;
#pragma unroll
      for (int r = 0; r < 4; ++r){ s0[r] = a00[r] + a01[r]; s1[r] = a10[r] + a11[r]; }
      *(f32x4*)&red[(wv*2 + 0)*264 + l*4] = s0;
      *(f32x4*)&red[(wv*2 + 1)*264 + l*4] = s1;
      __syncthreads();
    }

    // ---- elementwise (thread owns (bl, jl)) ----
    float gate[4];
    short xvv[4] = {xv0, xv1, xv2, xv3};
#pragma unroll
    for (int g = 0; g < 4; ++g){
      float rv = 0.f;
      if (t > 0){
        rv = red[((g*2 + 0)*2 + ct_r)*264 + lane_src*4 + rr]
           + red[((g*2 + 1)*2 + ct_r)*264 + lane_src*4 + rr];
      }
      gate[g] = rv + bf2f(xvv[g]);
    }
    float ii = sigm(gate[0]);
    float ff = sigm(gate[1]);
    float gg = tanh_(gate[2]);
    float oo = sigm(gate[3]);
    float c2 = ff*c + ii*gg;
    float h2 = oo*tanh_(c2);
    c = c2*mc;
    float hn = h2*mh;

    if (t == T_ - 1){
      if (LAYER == 0){
        out0[((long)(bt*16 + bl)*T_ + t)*H_ + jcol] = f2bf(h2*mo);
      } else {
        dout[((long)(bt*16 + bl)*T_ + t)*H_ + jcol] = h2*mo;
        dout[(long)B_*T_*H_ + bj] = hn;                    // hf
        dout[(long)B_*T_*H_ + (long)B_*H_ + bj] = c;       // cf
      }
      break;
    }

    // ---- wave-local pack: lane l -> sstage[wv*64+l]; lanes<8 store chunks ----
    sstage[wv*64 + l] = f2bf(hn);
    asm volatile("s_waitcnt lgkmcnt(0)" ::: "memory");   // own wave's ds_write done
    __builtin_amdgcn_sched_barrier(0);
    if (l < 8){
      short8 pk = *(const short8*)&sstage[wv*64 + l*8];
      char* hdst = (char*)hring + nslotoff
                 + ((long)bt*2048 + jb*64 + wv*8 + l)*16;
      if constexpr (RING){
        // fire-and-forget: sentinel protocol needs no ack
        asm volatile("global_store_dwordx4 %0, %1, off sc1" :: "v"(hdst), "v"(pk) : "memory");
      } else {
        union { short8 s; u64 q[2]; } uu; uu.s = pk;
        u64* qp = (u64*)hdst;
        __hip_atomic_store(qp,     uu.q[0], __ATOMIC_RELAXED, __HIP_MEMORY_SCOPE_AGENT);
        __hip_atomic_store(qp + 1, uu.q[1], __ATOMIC_RELAXED, __HIP_MEMORY_SCOPE_AGENT);
      }
    }
    if constexpr (!RING){
      asm volatile("s_waitcnt vmcnt(0)" ::: "memory");   // h at coherence point
      __syncthreads();
      if (tid == 0)
        __hip_atomic_store(&flbase[(long)t*32 + jb], 1,
                           __ATOMIC_RELAXED, __HIP_MEMORY_SCOPE_AGENT);
    }

    // ---- out stores + xg prefetch (overlap next-step poll/gather) ----
    if (LAYER == 0){
      out0[((long)(bt*16 + bl)*T_ + t)*H_ + jcol] = f2bf(h2*mo);
    } else {
      dout[((long)(bt*16 + bl)*T_ + t)*H_ + jcol] = h2*mo;
    }
    {
      const short* xp = xg + xbase + (long)(t + 1)*G4;
      xv0 = xp[0]; xv1 = xp[H_]; xv2 = xp[2*H_]; xv3 = xp[3*H_];
    }

    if constexpr (!RING){
      // fallback: poll 32 packed flags (16 lanes x u64)
      const u64* fp = (const u64*)&flbase[(long)t*32];
      int spins = 0;
      while (true){
        int ok = 1;
        if (l < 16){
          u64 v = __hip_atomic_load(fp + l, __ATOMIC_RELAXED, __HIP_MEMORY_SCOPE_AGENT);
          ok = ((unsigned)v != 0u) & ((unsigned)(v >> 32) != 0u);
        }
        if (__all(ok)) break;
        if (++spins > (1 << 20)) break;
        if (spins > 8) __builtin_amdgcn_s_sleep(1);
      }
      __builtin_amdgcn_sched_barrier(0);
      __builtin_amdgcn_fence(__ATOMIC_ACQUIRE, "workgroup");
    }
  }
}

extern "C" void kernel_launch(void* const* d_in, const int* in_sizes, int n_in,
                              void* d_out, int out_size, void* d_ws, size_t ws_size,
                              hipStream_t stream){
  const float* x    = (const float*)d_in[0];
  const float* Wih0 = (const float*)d_in[1];
  const float* Whh0 = (const float*)d_in[2];
  const float* bih0 = (const float*)d_in[3];
  const float* bhh0 = (const float*)d_in[4];
  const float* Wih1 = (const float*)d_in[5];
  const float* Whh1 = (const float*)d_in[6];
  const float* bih1 = (const float*)d_in[7];
  const float* bhh1 = (const float*)d_in[8];
  const float* omsk = (const float*)d_in[9];
  const float* hmsk = (const float*)d_in[10];
  const float* cmsk = (const float*)d_in[11];
  float* out = (float*)d_out;

  char* p = (char*)d_ws;
  auto alloc = [&](size_t bytes)->char*{
    char* r = p; p += (bytes + 255) & ~(size_t)255; return r;
  };
  short* xg      = (short*)alloc((size_t)65536*4096*2);   // 512 MB xg, natural [m][4096]
  short* out0_bf = (short*)alloc((size_t)67108864*2);     // 128 MB layer-0 outputs
  short* x_bf    = (short*)out0_bf;                       // 64 MB alias (dead before out0 written)
  short* wih0_bf = (short*)alloc((size_t)2097152*2);
  short* wih1_bf = (short*)alloc((size_t)4194304*2);
  short* whh0_sw = (short*)alloc((size_t)4194304*2);
  short* whh1_sw = (short*)alloc((size_t)4194304*2);
  int*   flags0  = (int*)alloc((size_t)8*512*32*4);       // fallback flags
  int*   flags1  = (int*)alloc((size_t)8*512*32*4);
  // ring if it fits, else 2-slot ping-pong fallback
  size_t fixed = (size_t)(p - (char*)d_ws);
  bool ring = (fixed + (size_t)512*SLOT) <= ws_size;
  size_t ringbytes = ring ? (size_t)512*SLOT : (size_t)2*SLOT;
  short* hring = (short*)alloc(ringbytes);
  if ((size_t)(p - (char*)d_ws) > ws_size) return;   // cannot even fit fallback — bail

  // ring pre-filled with sentinel (0xFF); fallback flags zeroed only if used
  if (!ring){
    hipMemsetAsync(flags0, 0, (size_t)8*512*32*4, stream);
    hipMemsetAsync(flags1, 0, (size_t)8*512*32*4, stream);
  }
  hipMemsetAsync(hring, 0xFF, ringbytes, stream);

  // converts / weight swizzles
  cvt_bf16<<<33554432/4/256, 256, 0, stream>>>(x,    x_bf,    33554432/4);
  cvt_bf16<<<2097152/4/256,  256, 0, stream>>>(Wih0, wih0_bf, 2097152/4);
  cvt_bf16<<<4194304/4/256,  256, 0, stream>>>(Wih1, wih1_bf, 4194304/4);
  swz_whh <<<524288/256,     256, 0, stream>>>(Whh0, whh0_sw);
  swz_whh <<<524288/256,     256, 0, stream>>>(Whh1, whh1_sw);

  // ---- layer 0 ----
  proj_gemm<512><<<dim3(32, 512), 256, 0, stream>>>(x_bf, wih0_bf, bih0, bhh0, xg);
  if (ring)
    lstm_scan<0, true ><<<dim3(8, 32), 512, 0, stream>>>(hring, whh0_sw, xg,
        omsk, hmsk, cmsk, out0_bf, nullptr, flags0);
  else
    lstm_scan<0, false><<<dim3(8, 32), 512, 0, stream>>>(hring, whh0_sw, xg,
        omsk, hmsk, cmsk, out0_bf, nullptr, flags0);

  // re-sentinel ring for layer 1 (slots must look unwritten again)
  hipMemsetAsync(hring, 0xFF, ringbytes, stream);

  // ---- layer 1 ----
  proj_gemm<1024><<<dim3(32, 512), 256, 0, stream>>>(out0_bf, wih1_bf, bih1, bhh1, xg);
  if (ring)
    lstm_scan<1, true ><<<dim3(8, 32), 512, 0, stream>>>(hring, whh1_sw, xg,
        omsk + 131072, hmsk + 131072, cmsk + 131072, nullptr, out, flags1);
  else
    lstm_scan<1, false><<<dim3(8, 32), 512, 0, stream>>>(hring, whh1_sw, xg,
        omsk + 131072, hmsk + 131072, cmsk + 131072, nullptr, out, flags1);
}